// Round 2
// baseline (1448.030 us; speedup 1.0000x reference)
//
#include <hip/hip_runtime.h>

#define N_PIX 16384
#define CC 192
#define C3 576

struct WPtrs { const float* p[4]; };

// ---------------- GEMM: Y[bt][m][n] = sum_k W[m][k] * X[bt][k][n] ----------------
// 64x64 tile per 256-thread block, 4x4 micro-tile, K in steps of 16.
__global__ __launch_bounds__(256) void gemm64(WPtrs wp, int bpw,
    const float* __restrict__ X, float* __restrict__ Y,
    int K, long sX, long sY)
{
    __shared__ float Wl[16][64];
    __shared__ float Xl[16][64];
    const int bt = blockIdx.z;
    const float* __restrict__ W = wp.p[bt / bpw];
    const float* __restrict__ Xb = X + (long)bt * sX;
    float* __restrict__ Yb = Y + (long)bt * sY;
    const int m0 = blockIdx.y * 64, n0 = blockIdx.x * 64;
    const int tid = threadIdx.x;
    const int tn = tid & 15, tm = tid >> 4;
    float acc[4][4] = {};
    for (int k0 = 0; k0 < K; k0 += 16) {
        {
            const int r = tid >> 2;            // 0..63 (m row)
            const int kk = (tid & 3) << 2;     // 0,4,8,12
            float4 wv = *(const float4*)(W + (long)(m0 + r) * K + k0 + kk);
            Wl[kk + 0][r] = wv.x; Wl[kk + 1][r] = wv.y;
            Wl[kk + 2][r] = wv.z; Wl[kk + 3][r] = wv.w;
        }
        {
            const int r = tid >> 4;            // 0..15 (k row)
            const int c = (tid & 15) << 2;     // 0..60
            *(float4*)(&Xl[r][c]) = *(const float4*)(Xb + (long)(k0 + r) * N_PIX + n0 + c);
        }
        __syncthreads();
        #pragma unroll
        for (int k = 0; k < 16; ++k) {
            float4 a4 = *(const float4*)(&Wl[k][tm << 2]);
            float4 b4 = *(const float4*)(&Xl[k][tn << 2]);
            float av[4] = {a4.x, a4.y, a4.z, a4.w};
            float bv[4] = {b4.x, b4.y, b4.z, b4.w};
            #pragma unroll
            for (int i = 0; i < 4; ++i)
                #pragma unroll
                for (int j = 0; j < 4; ++j)
                    acc[i][j] = fmaf(av[i], bv[j], acc[i][j]);
        }
        __syncthreads();
    }
    #pragma unroll
    for (int i = 0; i < 4; ++i) {
        float4 o = make_float4(acc[i][0], acc[i][1], acc[i][2], acc[i][3]);
        *(float4*)(Yb + (long)(m0 + tm * 4 + i) * N_PIX + n0 + tn * 4) = o;
    }
}

// ---------------- depthwise 3x3, pad 1 ----------------
__global__ __launch_bounds__(256) void dwconv3(const float* __restrict__ Yin,
    const float* __restrict__ wdw, float* __restrict__ Z)
{
    const int sb = blockIdx.z, ch = blockIdx.y;
    const int tid = threadIdx.x;
    const int y = (blockIdx.x << 1) + (tid >> 7);
    const int x = tid & 127;
    const float* __restrict__ inp = Yin + (long)(sb * C3 + ch) * N_PIX;
    const float* wch = wdw + ch * 9;
    float s = 0.f;
    #pragma unroll
    for (int dy = -1; dy <= 1; ++dy) {
        const int yy = y + dy;
        if (yy < 0 || yy > 127) continue;
        const float* row = inp + yy * 128;
        const float wl = wch[(dy + 1) * 3 + 0];
        const float wm = wch[(dy + 1) * 3 + 1];
        const float wr = wch[(dy + 1) * 3 + 2];
        if (x > 0)   s = fmaf(wl, row[x - 1], s);
        s = fmaf(wm, row[x], s);
        if (x < 127) s = fmaf(wr, row[x + 1], s);
    }
    Z[(long)(sb * C3 + ch) * N_PIX + (y << 7) + x] = s;
}

// ---------------- row inverse L2 norms for q,k ----------------
__global__ __launch_bounds__(256) void rownorm(const float* __restrict__ Z,
                                               float* __restrict__ invn)
{
    const int row = blockIdx.x;             // [0, 2*4*384)
    const int s = row / 1536;
    const int b = (row / 384) & 3;
    const int cc = row % 384;               // 0..191 q, 192..383 k
    const float* p = Z + (long)((s * 4 + b) * C3 + cc) * N_PIX;
    const int tid = threadIdx.x;
    float ss = 0.f;
    for (int i = tid * 4; i < N_PIX; i += 1024) {
        float4 v = *(const float4*)(p + i);
        ss += v.x * v.x + v.y * v.y + v.z * v.z + v.w * v.w;
    }
    #pragma unroll
    for (int off = 32; off > 0; off >>= 1) ss += __shfl_down(ss, off);
    __shared__ float red[4];
    if ((tid & 63) == 0) red[tid >> 6] = ss;
    __syncthreads();
    if (tid == 0) {
        float t = red[0] + red[1] + red[2] + red[3];
        invn[row] = 1.f / fmaxf(sqrtf(t), 1e-12f);
    }
}

// ---------------- raw score partials: part[m][b][h][chunk][48][48] ----------------
__global__ __launch_bounds__(256) void scores_part(const float* __restrict__ Z,
                                                   float* __restrict__ part)
{
    const int chunk = blockIdx.x;                    // 8 chunks of 2048
    const int b = blockIdx.y >> 2, h = blockIdx.y & 3;
    const int m = blockIdx.z;                        // combo
    const int qs = (m == 1 || m == 3) ? 1 : 0;
    const int ks = (m == 1 || m == 2) ? 1 : 0;
    const float* qp = Z + (long)((qs * 4 + b) * C3 + h * 48) * N_PIX;
    const float* kp = Z + (long)((ks * 4 + b) * C3 + 192 + h * 48) * N_PIX;
    __shared__ float qsm[48][132];
    __shared__ float ksm[48][132];
    const int tid = threadIdx.x;
    const int ty = tid >> 4, tx = tid & 15;
    float acc[3][3] = {};
    const int nbase = chunk * 2048;
    for (int nb = 0; nb < 2048; nb += 128) {
        for (int l = tid; l < 48 * 32; l += 256) {
            const int r = l >> 5, c = (l & 31) << 2;
            *(float4*)(&qsm[r][c]) = *(const float4*)(qp + (long)r * N_PIX + nbase + nb + c);
            *(float4*)(&ksm[r][c]) = *(const float4*)(kp + (long)r * N_PIX + nbase + nb + c);
        }
        __syncthreads();
        #pragma unroll 4
        for (int nn = 0; nn < 128; nn += 4) {
            float4 qv[3], kv[3];
            #pragma unroll
            for (int i = 0; i < 3; ++i) qv[i] = *(const float4*)(&qsm[ty * 3 + i][nn]);
            #pragma unroll
            for (int j = 0; j < 3; ++j) kv[j] = *(const float4*)(&ksm[tx * 3 + j][nn]);
            #pragma unroll
            for (int i = 0; i < 3; ++i)
                #pragma unroll
                for (int j = 0; j < 3; ++j)
                    acc[i][j] += qv[i].x * kv[j].x + qv[i].y * kv[j].y +
                                 qv[i].z * kv[j].z + qv[i].w * kv[j].w;
        }
        __syncthreads();
    }
    const long base = (((long)(m * 16 + b * 4 + h)) * 8 + chunk) * 2304;
    #pragma unroll
    for (int i = 0; i < 3; ++i)
        #pragma unroll
        for (int j = 0; j < 3; ++j)
            part[base + (ty * 3 + i) * 48 + (tx * 3 + j)] = acc[i][j];
}

// ---------------- reduce partials, scale by norms+temperature, softmax ----------------
__global__ __launch_bounds__(256) void reduce_softmax(const float* __restrict__ part,
    const float* __restrict__ invn, const float* __restrict__ temp,
    float* __restrict__ attn)
{
    const int mbh = blockIdx.x;                 // 64
    const int m = mbh >> 4, b = (mbh >> 2) & 3, h = mbh & 3;
    const int qs = (m == 1 || m == 3) ? 1 : 0;
    const int ks = (m == 1 || m == 2) ? 1 : 0;
    __shared__ float sm[48][48];
    const int tid = threadIdx.x;
    const long pbase = (long)mbh * 8 * 2304;
    const float T = temp[h];
    for (int idx = tid; idx < 2304; idx += 256) {
        float v = 0.f;
        #pragma unroll
        for (int c = 0; c < 8; ++c) v += part[pbase + c * 2304 + idx];
        const int d = idx / 48, e = idx % 48;
        const float iq = invn[(qs * 4 + b) * 384 + h * 48 + d];
        const float ik = invn[(ks * 4 + b) * 384 + 192 + h * 48 + e];
        sm[d][e] = v * iq * ik * T;
    }
    __syncthreads();
    if (tid < 48) {
        float mx = -1e30f;
        #pragma unroll
        for (int e = 0; e < 48; ++e) mx = fmaxf(mx, sm[tid][e]);
        float sum = 0.f;
        #pragma unroll
        for (int e = 0; e < 48; ++e) {
            const float v = __expf(sm[tid][e] - mx);
            sm[tid][e] = v;
            sum += v;
        }
        const float inv = 1.f / sum;
        const long abase = (long)mbh * 2304 + (long)tid * 48;
        #pragma unroll
        for (int e = 0; e < 48; ++e) attn[abase + e] = sm[tid][e] * inv;
    }
}

// ---------------- att_out[m][b][h*48+d][n] = sum_e A[d][e] * v[e][n] ----------------
// m==3 (inter_de): reference einsum '...de,bhen->bhdn' SUMS the ellipsis dims,
// so A = sum over all 16 (b,h) of attn_de, applied identically to every (b,h).
__global__ __launch_bounds__(256) void attnv(const float* __restrict__ Z,
    const float* __restrict__ attn, float* __restrict__ AO)
{
    const int nt = blockIdx.x;                  // 16 tiles of 1024 cols
    const int b = blockIdx.y >> 2, h = blockIdx.y & 3;
    const int m = blockIdx.z;
    const int ks = (m == 1 || m == 2) ? 1 : 0;  // v source follows k
    const float* vp = Z + (long)((ks * 4 + b) * C3 + 384 + h * 48) * N_PIX;
    __shared__ float at[48][48];                // transposed: at[e][d]
    const int tid = threadIdx.x;
    if (m == 3) {
        for (int l = tid; l < 2304; l += 256) {
            float s = 0.f;
            #pragma unroll
            for (int bb = 0; bb < 16; ++bb)
                s += attn[(long)(48 + bb) * 2304 + l];
            at[l % 48][l / 48] = s;
        }
    } else {
        const long abase = (long)(m * 16 + b * 4 + h) * 2304;
        for (int l = tid; l < 2304; l += 256)
            at[l % 48][l / 48] = attn[abase + l];
    }
    __syncthreads();
    const int nn = (nt << 10) + (tid << 2);
    float* ao = AO + (long)((m * 4 + b) * CC + h * 48) * N_PIX;
    for (int d0 = 0; d0 < 48; d0 += 8) {
        float4 acc[8] = {};
        for (int e = 0; e < 48; ++e) {
            const float4 v = *(const float4*)(vp + (long)e * N_PIX + nn);
            #pragma unroll
            for (int i = 0; i < 8; ++i) {
                const float w = at[e][d0 + i];
                acc[i].x = fmaf(v.x, w, acc[i].x);
                acc[i].y = fmaf(v.y, w, acc[i].y);
                acc[i].z = fmaf(v.z, w, acc[i].z);
                acc[i].w = fmaf(v.w, w, acc[i].w);
            }
        }
        #pragma unroll
        for (int i = 0; i < 8; ++i)
            *(float4*)(ao + (long)(d0 + i) * N_PIX + nn) = acc[i];
    }
}

extern "C" void kernel_launch(void* const* d_in, const int* in_sizes, int n_in,
                              void* d_out, int out_size, void* d_ws, size_t ws_size,
                              hipStream_t stream)
{
    const float* e     = (const float*)d_in[0];
    const float* d     = (const float*)d_in[1];
    const float* temp  = (const float*)d_in[2];
    const float* w_qkv = (const float*)d_in[3];
    const float* w_dw  = (const float*)d_in[4];
    const float* w_p1  = (const float*)d_in[5];
    const float* w_p2  = (const float*)d_in[6];
    const float* w_p3  = (const float*)d_in[7];
    const float* w_p4  = (const float*)d_in[8];
    float* out = (float*)d_out;
    float* ws  = (float*)d_ws;

    // workspace layout (floats)
    float* z_raw = ws;                      // 2*4*576*16384 = 75,497,472
    float* z     = ws + 75497472L;          // 75,497,472
    float* part  = ws + 150994944L;         // 4*4*4*8*2304 = 1,179,648
    float* attn  = ws + 152174592L;         // 147,456
    float* invn  = ws + 152322048L;         // 3,072
    // total 152,325,120 floats = 609.3 MB

    WPtrs wq; wq.p[0] = w_qkv; wq.p[1] = w_qkv; wq.p[2] = w_qkv; wq.p[3] = w_qkv;
    const long sXin = (long)CC * N_PIX;     // 192*16384
    const long sQKV = (long)C3 * N_PIX;     // 576*16384

    // 1) pointwise qkv GEMM for e (batches 0..3) and d (batches 4..7)
    gemm64<<<dim3(256, 9, 4), 256, 0, stream>>>(wq, 4, e, z_raw, CC, sXin, sQKV);
    gemm64<<<dim3(256, 9, 4), 256, 0, stream>>>(wq, 4, d, z_raw + 4L * sQKV, CC, sXin, sQKV);
    // 2) depthwise 3x3
    dwconv3<<<dim3(64, C3, 8), 256, 0, stream>>>(z_raw, w_dw, z);
    // 3) inverse L2 norms for q,k rows
    rownorm<<<dim3(3072), 256, 0, stream>>>(z, invn);
    // 4) score partials (deterministic two-phase)
    scores_part<<<dim3(8, 16, 4), 256, 0, stream>>>(z, part);
    // 5) reduce + scale + softmax
    reduce_softmax<<<dim3(64), 256, 0, stream>>>(part, invn, temp, attn);
    // 6) attn @ v  (att_out reuses z_raw region)
    float* ao = z_raw;
    attnv<<<dim3(16, 16, 4), 256, 0, stream>>>(z, attn, ao);
    // 7) output projections into d_out
    WPtrs wpj; wpj.p[0] = w_p1; wpj.p[1] = w_p2; wpj.p[2] = w_p3; wpj.p[3] = w_p4;
    gemm64<<<dim3(256, 3, 16), 256, 0, stream>>>(wpj, 4, ao, out, CC, sXin, sXin);
}

// Round 3
// 1116.839 us; speedup vs baseline: 1.2965x; 1.2965x over previous
//
#include <hip/hip_runtime.h>

#define N_PIX 16384
#define CC 192
#define C3 576

struct WPtrs { const float* p[4]; };

// ---------------- GEMM: Y[bt][m][n] = sum_k W[m][k] * X[bt][k][n] ----------------
// 64x64 tile per 256-thread block, 4x4 micro-tile, K in steps of 16.
__global__ __launch_bounds__(256) void gemm64(WPtrs wp, int bpw,
    const float* __restrict__ X, float* __restrict__ Y,
    int K, long sX, long sY)
{
    __shared__ float Wl[16][64];
    __shared__ float Xl[16][64];
    const int bt = blockIdx.z;
    const float* __restrict__ W = wp.p[bt / bpw];
    const float* __restrict__ Xb = X + (long)bt * sX;
    float* __restrict__ Yb = Y + (long)bt * sY;
    const int m0 = blockIdx.y * 64, n0 = blockIdx.x * 64;
    const int tid = threadIdx.x;
    const int tn = tid & 15, tm = tid >> 4;
    float acc[4][4] = {};
    for (int k0 = 0; k0 < K; k0 += 16) {
        {
            const int r = tid >> 2;            // 0..63 (m row)
            const int kk = (tid & 3) << 2;     // 0,4,8,12
            float4 wv = *(const float4*)(W + (long)(m0 + r) * K + k0 + kk);
            Wl[kk + 0][r] = wv.x; Wl[kk + 1][r] = wv.y;
            Wl[kk + 2][r] = wv.z; Wl[kk + 3][r] = wv.w;
        }
        {
            const int r = tid >> 4;            // 0..15 (k row)
            const int c = (tid & 15) << 2;     // 0..60
            *(float4*)(&Xl[r][c]) = *(const float4*)(Xb + (long)(k0 + r) * N_PIX + n0 + c);
        }
        __syncthreads();
        #pragma unroll
        for (int k = 0; k < 16; ++k) {
            float4 a4 = *(const float4*)(&Wl[k][tm << 2]);
            float4 b4 = *(const float4*)(&Xl[k][tn << 2]);
            float av[4] = {a4.x, a4.y, a4.z, a4.w};
            float bv[4] = {b4.x, b4.y, b4.z, b4.w};
            #pragma unroll
            for (int i = 0; i < 4; ++i)
                #pragma unroll
                for (int j = 0; j < 4; ++j)
                    acc[i][j] = fmaf(av[i], bv[j], acc[i][j]);
        }
        __syncthreads();
    }
    #pragma unroll
    for (int i = 0; i < 4; ++i) {
        float4 o = make_float4(acc[i][0], acc[i][1], acc[i][2], acc[i][3]);
        *(float4*)(Yb + (long)(m0 + tm * 4 + i) * N_PIX + n0 + tn * 4) = o;
    }
}

// ---------------- depthwise 3x3, pad 1 — register-rolling 4x8 strip per thread ----
__global__ __launch_bounds__(256) void dwconv3(const float* __restrict__ Yin,
    const float* __restrict__ wdw, float* __restrict__ Z)
{
    const int sb = blockIdx.z, ch = blockIdx.y;
    const int tid = threadIdx.x;
    const int x0 = (tid & 31) << 2;                         // 0..124
    const int y0 = (blockIdx.x << 6) + ((tid >> 5) << 3);   // strip of 8 rows
    const float* __restrict__ inp = Yin + (long)(sb * C3 + ch) * N_PIX;
    float* __restrict__ outp = Z + (long)(sb * C3 + ch) * N_PIX;
    const float* wch = wdw + ch * 9;
    const float w00 = wch[0], w01 = wch[1], w02 = wch[2];
    const float w10 = wch[3], w11 = wch[4], w12 = wch[5];
    const float w20 = wch[6], w21 = wch[7], w22 = wch[8];
    const bool hasL = (x0 > 0), hasR = (x0 < 124);
    float A[6], B[6], Cr[6];   // [0]=x0-1, [1..4]=x0..x0+3, [5]=x0+4
    auto loadrow = [&](int yy, float* r) {
        if (yy < 0 || yy > 127) {
            r[0] = r[1] = r[2] = r[3] = r[4] = r[5] = 0.f; return;
        }
        const float* p = inp + (yy << 7);
        const float4 v = *(const float4*)(p + x0);
        r[1] = v.x; r[2] = v.y; r[3] = v.z; r[4] = v.w;
        r[0] = hasL ? p[x0 - 1] : 0.f;
        r[5] = hasR ? p[x0 + 4] : 0.f;
    };
    loadrow(y0 - 1, A);
    loadrow(y0,     B);
    #pragma unroll
    for (int r = 0; r < 8; ++r) {
        loadrow(y0 + r + 1, Cr);
        float o[4];
        #pragma unroll
        for (int i = 0; i < 4; ++i) {
            float s;
            s = fmaf(w00, A[i],  fmaf(w01, A[i + 1],  w02 * A[i + 2]));
            s = fmaf(w10, B[i],  fmaf(w11, B[i + 1],  fmaf(w12, B[i + 2], s)));
            s = fmaf(w20, Cr[i], fmaf(w21, Cr[i + 1], fmaf(w22, Cr[i + 2], s)));
            o[i] = s;
        }
        *(float4*)(outp + ((y0 + r) << 7) + x0) = make_float4(o[0], o[1], o[2], o[3]);
        #pragma unroll
        for (int i = 0; i < 6; ++i) { A[i] = B[i]; B[i] = Cr[i]; }
    }
}

// ---------------- row inverse L2 norms for q,k ----------------
__global__ __launch_bounds__(256) void rownorm(const float* __restrict__ Z,
                                               float* __restrict__ invn)
{
    const int row = blockIdx.x;             // [0, 2*4*384)
    const int s = row / 1536;
    const int b = (row / 384) & 3;
    const int cc = row % 384;               // 0..191 q, 192..383 k
    const float* p = Z + (long)((s * 4 + b) * C3 + cc) * N_PIX;
    const int tid = threadIdx.x;
    float ss = 0.f;
    for (int i = tid * 4; i < N_PIX; i += 1024) {
        float4 v = *(const float4*)(p + i);
        ss += v.x * v.x + v.y * v.y + v.z * v.z + v.w * v.w;
    }
    #pragma unroll
    for (int off = 32; off > 0; off >>= 1) ss += __shfl_down(ss, off);
    __shared__ float red[4];
    if ((tid & 63) == 0) red[tid >> 6] = ss;
    __syncthreads();
    if (tid == 0) {
        float t = red[0] + red[1] + red[2] + red[3];
        invn[row] = 1.f / fmaxf(sqrtf(t), 1e-12f);
    }
}

// ---------------- raw score partials: part[m][b][h][chunk][48][48] ----------------
__global__ __launch_bounds__(256) void scores_part(const float* __restrict__ Z,
                                                   float* __restrict__ part)
{
    const int chunk = blockIdx.x;                    // 8 chunks of 2048
    const int b = blockIdx.y >> 2, h = blockIdx.y & 3;
    const int m = blockIdx.z;                        // combo
    const int qs = (m == 1 || m == 3) ? 1 : 0;
    const int ks = (m == 1 || m == 2) ? 1 : 0;
    const float* qp = Z + (long)((qs * 4 + b) * C3 + h * 48) * N_PIX;
    const float* kp = Z + (long)((ks * 4 + b) * C3 + 192 + h * 48) * N_PIX;
    __shared__ float qsm[48][132];
    __shared__ float ksm[48][132];
    const int tid = threadIdx.x;
    const int ty = tid >> 4, tx = tid & 15;
    float acc[3][3] = {};
    const int nbase = chunk * 2048;
    for (int nb = 0; nb < 2048; nb += 128) {
        for (int l = tid; l < 48 * 32; l += 256) {
            const int r = l >> 5, c = (l & 31) << 2;
            *(float4*)(&qsm[r][c]) = *(const float4*)(qp + (long)r * N_PIX + nbase + nb + c);
            *(float4*)(&ksm[r][c]) = *(const float4*)(kp + (long)r * N_PIX + nbase + nb + c);
        }
        __syncthreads();
        #pragma unroll 4
        for (int nn = 0; nn < 128; nn += 4) {
            float4 qv[3], kv[3];
            #pragma unroll
            for (int i = 0; i < 3; ++i) qv[i] = *(const float4*)(&qsm[ty * 3 + i][nn]);
            #pragma unroll
            for (int j = 0; j < 3; ++j) kv[j] = *(const float4*)(&ksm[tx * 3 + j][nn]);
            #pragma unroll
            for (int i = 0; i < 3; ++i)
                #pragma unroll
                for (int j = 0; j < 3; ++j)
                    acc[i][j] += qv[i].x * kv[j].x + qv[i].y * kv[j].y +
                                 qv[i].z * kv[j].z + qv[i].w * kv[j].w;
        }
        __syncthreads();
    }
    const long base = (((long)(m * 16 + b * 4 + h)) * 8 + chunk) * 2304;
    #pragma unroll
    for (int i = 0; i < 3; ++i)
        #pragma unroll
        for (int j = 0; j < 3; ++j)
            part[base + (ty * 3 + i) * 48 + (tx * 3 + j)] = acc[i][j];
}

// ---------------- reduce partials, scale by norms+temperature, softmax ----------------
__global__ __launch_bounds__(256) void reduce_softmax(const float* __restrict__ part,
    const float* __restrict__ invn, const float* __restrict__ temp,
    float* __restrict__ attn)
{
    const int mbh = blockIdx.x;                 // 64
    const int m = mbh >> 4, b = (mbh >> 2) & 3, h = mbh & 3;
    const int qs = (m == 1 || m == 3) ? 1 : 0;
    const int ks = (m == 1 || m == 2) ? 1 : 0;
    __shared__ float sm[48][48];
    const int tid = threadIdx.x;
    const long pbase = (long)mbh * 8 * 2304;
    const float T = temp[h];
    for (int idx = tid; idx < 2304; idx += 256) {
        float v = 0.f;
        #pragma unroll
        for (int c = 0; c < 8; ++c) v += part[pbase + c * 2304 + idx];
        const int d = idx / 48, e = idx % 48;
        const float iq = invn[(qs * 4 + b) * 384 + h * 48 + d];
        const float ik = invn[(ks * 4 + b) * 384 + 192 + h * 48 + e];
        sm[d][e] = v * iq * ik * T;
    }
    __syncthreads();
    if (tid < 48) {
        float mx = -1e30f;
        #pragma unroll
        for (int e = 0; e < 48; ++e) mx = fmaxf(mx, sm[tid][e]);
        float sum = 0.f;
        #pragma unroll
        for (int e = 0; e < 48; ++e) {
            const float v = __expf(sm[tid][e] - mx);
            sm[tid][e] = v;
            sum += v;
        }
        const float inv = 1.f / sum;
        const long abase = (long)mbh * 2304 + (long)tid * 48;
        #pragma unroll
        for (int e = 0; e < 48; ++e) attn[abase + e] = sm[tid][e] * inv;
    }
}

// ---------------- att_out[m][b][h*48+d][n] = sum_e A[d][e] * v[e][n] ----------------
// m==3 (inter_de): reference einsum '...de,bhen->bhdn' SUMS the ellipsis dims,
// so A = sum over all 16 (b,h) of attn_de, applied identically to every (b,h).
__global__ __launch_bounds__(256) void attnv(const float* __restrict__ Z,
    const float* __restrict__ attn, float* __restrict__ AO)
{
    const int nt = blockIdx.x;                  // 16 tiles of 1024 cols
    const int b = blockIdx.y >> 2, h = blockIdx.y & 3;
    const int m = blockIdx.z;
    const int ks = (m == 1 || m == 2) ? 1 : 0;  // v source follows k
    const float* vp = Z + (long)((ks * 4 + b) * C3 + 384 + h * 48) * N_PIX;
    __shared__ float at[48][48];                // transposed: at[e][d]
    const int tid = threadIdx.x;
    if (m == 3) {
        for (int l = tid; l < 2304; l += 256) {
            float s = 0.f;
            #pragma unroll
            for (int bb = 0; bb < 16; ++bb)
                s += attn[(long)(48 + bb) * 2304 + l];
            at[l % 48][l / 48] = s;
        }
    } else {
        const long abase = (long)(m * 16 + b * 4 + h) * 2304;
        for (int l = tid; l < 2304; l += 256)
            at[l % 48][l / 48] = attn[abase + l];
    }
    __syncthreads();
    const int nn = (nt << 10) + (tid << 2);
    float* ao = AO + (long)((m * 4 + b) * CC + h * 48) * N_PIX;
    for (int d0 = 0; d0 < 48; d0 += 8) {
        float4 acc[8] = {};
        for (int e = 0; e < 48; ++e) {
            const float4 v = *(const float4*)(vp + (long)e * N_PIX + nn);
            #pragma unroll
            for (int i = 0; i < 8; ++i) {
                const float w = at[e][d0 + i];
                acc[i].x = fmaf(v.x, w, acc[i].x);
                acc[i].y = fmaf(v.y, w, acc[i].y);
                acc[i].z = fmaf(v.z, w, acc[i].z);
                acc[i].w = fmaf(v.w, w, acc[i].w);
            }
        }
        #pragma unroll
        for (int i = 0; i < 8; ++i)
            *(float4*)(ao + (long)(d0 + i) * N_PIX + nn) = acc[i];
    }
}

extern "C" void kernel_launch(void* const* d_in, const int* in_sizes, int n_in,
                              void* d_out, int out_size, void* d_ws, size_t ws_size,
                              hipStream_t stream)
{
    const float* e     = (const float*)d_in[0];
    const float* d     = (const float*)d_in[1];
    const float* temp  = (const float*)d_in[2];
    const float* w_qkv = (const float*)d_in[3];
    const float* w_dw  = (const float*)d_in[4];
    const float* w_p1  = (const float*)d_in[5];
    const float* w_p2  = (const float*)d_in[6];
    const float* w_p3  = (const float*)d_in[7];
    const float* w_p4  = (const float*)d_in[8];
    float* out = (float*)d_out;
    float* ws  = (float*)d_ws;

    // workspace layout (floats)
    float* z_raw = ws;                      // 2*4*576*16384 = 75,497,472
    float* z     = ws + 75497472L;          // 75,497,472
    float* part  = ws + 150994944L;         // 4*4*4*8*2304 = 1,179,648
    float* attn  = ws + 152174592L;         // 147,456
    float* invn  = ws + 152322048L;         // 3,072
    // total 152,325,120 floats = 609.3 MB

    WPtrs wq; wq.p[0] = w_qkv; wq.p[1] = w_qkv; wq.p[2] = w_qkv; wq.p[3] = w_qkv;
    const long sXin = (long)CC * N_PIX;     // 192*16384
    const long sQKV = (long)C3 * N_PIX;     // 576*16384

    // 1) pointwise qkv GEMM for e (batches 0..3) and d (batches 4..7)
    gemm64<<<dim3(256, 9, 4), 256, 0, stream>>>(wq, 4, e, z_raw, CC, sXin, sQKV);
    gemm64<<<dim3(256, 9, 4), 256, 0, stream>>>(wq, 4, d, z_raw + 4L * sQKV, CC, sXin, sQKV);
    // 2) depthwise 3x3
    dwconv3<<<dim3(2, C3, 8), 256, 0, stream>>>(z_raw, w_dw, z);
    // 3) inverse L2 norms for q,k rows
    rownorm<<<dim3(3072), 256, 0, stream>>>(z, invn);
    // 4) score partials (deterministic two-phase)
    scores_part<<<dim3(8, 16, 4), 256, 0, stream>>>(z, part);
    // 5) reduce + scale + softmax
    reduce_softmax<<<dim3(64), 256, 0, stream>>>(part, invn, temp, attn);
    // 6) attn @ v  (att_out reuses z_raw region)
    float* ao = z_raw;
    attnv<<<dim3(16, 16, 4), 256, 0, stream>>>(z, attn, ao);
    // 7) output projections into d_out
    WPtrs wpj; wpj.p[0] = w_p1; wpj.p[1] = w_p2; wpj.p[2] = w_p3; wpj.p[3] = w_p4;
    gemm64<<<dim3(256, 3, 16), 256, 0, stream>>>(wpj, 4, ao, out, CC, sXin, sXin);
}

// Round 4
// 855.674 us; speedup vs baseline: 1.6923x; 1.3052x over previous
//
#include <hip/hip_runtime.h>

#define N_PIX 16384
#define CC 192
#define C3 576
#define KTOT 192

typedef __bf16 bf16_t;
typedef bf16_t bf16x4 __attribute__((ext_vector_type(4)));
typedef bf16_t bf16x8 __attribute__((ext_vector_type(8)));
typedef float f32x4 __attribute__((ext_vector_type(4)));

struct WPtrs { const float* p[4]; };

// ---------------- MFMA GEMM: Y[bt][m][n] = sum_k W[m][k] * X[bt][k][n] --------
// fp32 global in/out, bf16 LDS tiles, 64m x 256n block tile, K-step 32.
// A/B fragments use the same k-bijection phi(gi,e)=16*(e>>2)+4*gi+(e&3), so the
// contraction is correct for any HW k-map (A/B layouts are k-symmetric).
__global__ __launch_bounds__(256) void gemm_mfma(WPtrs wp, int bpw,
    const float* __restrict__ X, float* __restrict__ Y, long sX, long sY)
{
    __shared__ __align__(16) bf16_t Wl[64][36];    // 64 m x 32 k (+pad)
    __shared__ __align__(16) bf16_t Xl[256][36];   // 256 n x 32 k (+pad), transposed
    const int bt = blockIdx.z;
    const float* __restrict__ W = wp.p[bt / bpw];
    const float* __restrict__ Xb = X + (long)bt * sX;
    float* __restrict__ Yb = Y + (long)bt * sY;
    const int m0 = blockIdx.y * 64, n0 = blockIdx.x * 256;
    const int tid = threadIdx.x;
    const int w = tid >> 6;              // wave id: n-offset 64*w
    const int gi = (tid >> 4) & 3;       // lane>>4
    const int li = tid & 15;             // lane&15

    f32x4 acc[4][4];
    #pragma unroll
    for (int i = 0; i < 4; ++i)
        #pragma unroll
        for (int j = 0; j < 4; ++j) acc[i][j] = 0.f;

    const int wm = tid >> 2, wk = (tid & 3) << 3;   // W staging coords

    for (int k0 = 0; k0 < KTOT; k0 += 32) {
        // stage W tile 64x32 (k contiguous per row)
        {
            const float* wp0 = W + (long)(m0 + wm) * KTOT + k0 + wk;
            float4 a = *(const float4*)(wp0);
            float4 b = *(const float4*)(wp0 + 4);
            bf16x4 lo = { (bf16_t)a.x, (bf16_t)a.y, (bf16_t)a.z, (bf16_t)a.w };
            bf16x4 hi = { (bf16_t)b.x, (bf16_t)b.y, (bf16_t)b.z, (bf16_t)b.w };
            *(bf16x4*)&Wl[wm][wk]     = lo;
            *(bf16x4*)&Wl[wm][wk + 4] = hi;
        }
        // stage X tile 32k x 256n, transposed into Xl[n][k]
        {
            const float* xp = Xb + (long)k0 * N_PIX + n0 + tid;   // column tid
            #pragma unroll
            for (int g = 0; g < 8; ++g) {
                float x0 = xp[(long)(4 * g + 0) * N_PIX];
                float x1 = xp[(long)(4 * g + 1) * N_PIX];
                float x2 = xp[(long)(4 * g + 2) * N_PIX];
                float x3 = xp[(long)(4 * g + 3) * N_PIX];
                bf16x4 v = { (bf16_t)x0, (bf16_t)x1, (bf16_t)x2, (bf16_t)x3 };
                *(bf16x4*)&Xl[tid][g * 4] = v;
            }
        }
        __syncthreads();
        bf16x8 af[4], bfr[4];
        #pragma unroll
        for (int mi = 0; mi < 4; ++mi) {
            bf16x4 lo = *(const bf16x4*)&Wl[16 * mi + li][4 * gi];
            bf16x4 hi = *(const bf16x4*)&Wl[16 * mi + li][16 + 4 * gi];
            af[mi] = __builtin_shufflevector(lo, hi, 0, 1, 2, 3, 4, 5, 6, 7);
        }
        #pragma unroll
        for (int ni = 0; ni < 4; ++ni) {
            const int n = 64 * w + 16 * ni + li;
            bf16x4 lo = *(const bf16x4*)&Xl[n][4 * gi];
            bf16x4 hi = *(const bf16x4*)&Xl[n][16 + 4 * gi];
            bfr[ni] = __builtin_shufflevector(lo, hi, 0, 1, 2, 3, 4, 5, 6, 7);
        }
        #pragma unroll
        for (int mi = 0; mi < 4; ++mi)
            #pragma unroll
            for (int ni = 0; ni < 4; ++ni)
                acc[mi][ni] = __builtin_amdgcn_mfma_f32_16x16x32_bf16(
                    af[mi], bfr[ni], acc[mi][ni], 0, 0, 0);
        __syncthreads();
    }
    // epilogue: C/D map col=lane&15, row=4*(lane>>4)+reg  [m89-verified]
    #pragma unroll
    for (int mi = 0; mi < 4; ++mi) {
        #pragma unroll
        for (int ni = 0; ni < 4; ++ni) {
            const int n = n0 + 64 * w + 16 * ni + li;
            #pragma unroll
            for (int r = 0; r < 4; ++r) {
                const int m = m0 + 16 * mi + 4 * gi + r;
                Yb[(long)m * N_PIX + n] = acc[mi][ni][r];
            }
        }
    }
}

// ---------------- depthwise 3x3, pad 1 — register-rolling 4x8 strip per thread ----
__global__ __launch_bounds__(256) void dwconv3(const float* __restrict__ Yin,
    const float* __restrict__ wdw, float* __restrict__ Z)
{
    const int sb = blockIdx.z, ch = blockIdx.y;
    const int tid = threadIdx.x;
    const int x0 = (tid & 31) << 2;                         // 0..124
    const int y0 = (blockIdx.x << 6) + ((tid >> 5) << 3);   // strip of 8 rows
    const float* __restrict__ inp = Yin + (long)(sb * C3 + ch) * N_PIX;
    float* __restrict__ outp = Z + (long)(sb * C3 + ch) * N_PIX;
    const float* wch = wdw + ch * 9;
    const float w00 = wch[0], w01 = wch[1], w02 = wch[2];
    const float w10 = wch[3], w11 = wch[4], w12 = wch[5];
    const float w20 = wch[6], w21 = wch[7], w22 = wch[8];
    const bool hasL = (x0 > 0), hasR = (x0 < 124);
    float A[6], B[6], Cr[6];   // [0]=x0-1, [1..4]=x0..x0+3, [5]=x0+4
    auto loadrow = [&](int yy, float* r) {
        if (yy < 0 || yy > 127) {
            r[0] = r[1] = r[2] = r[3] = r[4] = r[5] = 0.f; return;
        }
        const float* p = inp + (yy << 7);
        const float4 v = *(const float4*)(p + x0);
        r[1] = v.x; r[2] = v.y; r[3] = v.z; r[4] = v.w;
        r[0] = hasL ? p[x0 - 1] : 0.f;
        r[5] = hasR ? p[x0 + 4] : 0.f;
    };
    loadrow(y0 - 1, A);
    loadrow(y0,     B);
    #pragma unroll
    for (int r = 0; r < 8; ++r) {
        loadrow(y0 + r + 1, Cr);
        float o[4];
        #pragma unroll
        for (int i = 0; i < 4; ++i) {
            float s;
            s = fmaf(w00, A[i],  fmaf(w01, A[i + 1],  w02 * A[i + 2]));
            s = fmaf(w10, B[i],  fmaf(w11, B[i + 1],  fmaf(w12, B[i + 2], s)));
            s = fmaf(w20, Cr[i], fmaf(w21, Cr[i + 1], fmaf(w22, Cr[i + 2], s)));
            o[i] = s;
        }
        *(float4*)(outp + ((y0 + r) << 7) + x0) = make_float4(o[0], o[1], o[2], o[3]);
        #pragma unroll
        for (int i = 0; i < 6; ++i) { A[i] = B[i]; B[i] = Cr[i]; }
    }
}

// ---------------- row inverse L2 norms for q,k ----------------
__global__ __launch_bounds__(256) void rownorm(const float* __restrict__ Z,
                                               float* __restrict__ invn)
{
    const int row = blockIdx.x;             // [0, 2*4*384)
    const int s = row / 1536;
    const int b = (row / 384) & 3;
    const int cc = row % 384;               // 0..191 q, 192..383 k
    const float* p = Z + (long)((s * 4 + b) * C3 + cc) * N_PIX;
    const int tid = threadIdx.x;
    float ss = 0.f;
    for (int i = tid * 4; i < N_PIX; i += 1024) {
        float4 v = *(const float4*)(p + i);
        ss += v.x * v.x + v.y * v.y + v.z * v.z + v.w * v.w;
    }
    #pragma unroll
    for (int off = 32; off > 0; off >>= 1) ss += __shfl_down(ss, off);
    __shared__ float red[4];
    if ((tid & 63) == 0) red[tid >> 6] = ss;
    __syncthreads();
    if (tid == 0) {
        float t = red[0] + red[1] + red[2] + red[3];
        invn[row] = 1.f / fmaxf(sqrtf(t), 1e-12f);
    }
}

// ---------------- raw score partials: part[m][b][h][chunk][48][48] ----------------
__global__ __launch_bounds__(256) void scores_part(const float* __restrict__ Z,
                                                   float* __restrict__ part)
{
    const int chunk = blockIdx.x;                    // 8 chunks of 2048
    const int b = blockIdx.y >> 2, h = blockIdx.y & 3;
    const int m = blockIdx.z;                        // combo
    const int qs = (m == 1 || m == 3) ? 1 : 0;
    const int ks = (m == 1 || m == 2) ? 1 : 0;
    const float* qp = Z + (long)((qs * 4 + b) * C3 + h * 48) * N_PIX;
    const float* kp = Z + (long)((ks * 4 + b) * C3 + 192 + h * 48) * N_PIX;
    __shared__ float qsm[48][132];
    __shared__ float ksm[48][132];
    const int tid = threadIdx.x;
    const int ty = tid >> 4, tx = tid & 15;
    float acc[3][3] = {};
    const int nbase = chunk * 2048;
    for (int nb = 0; nb < 2048; nb += 128) {
        for (int l = tid; l < 48 * 32; l += 256) {
            const int r = l >> 5, c = (l & 31) << 2;
            *(float4*)(&qsm[r][c]) = *(const float4*)(qp + (long)r * N_PIX + nbase + nb + c);
            *(float4*)(&ksm[r][c]) = *(const float4*)(kp + (long)r * N_PIX + nbase + nb + c);
        }
        __syncthreads();
        #pragma unroll 4
        for (int nn = 0; nn < 128; nn += 4) {
            float4 qv[3], kv[3];
            #pragma unroll
            for (int i = 0; i < 3; ++i) qv[i] = *(const float4*)(&qsm[ty * 3 + i][nn]);
            #pragma unroll
            for (int j = 0; j < 3; ++j) kv[j] = *(const float4*)(&ksm[tx * 3 + j][nn]);
            #pragma unroll
            for (int i = 0; i < 3; ++i)
                #pragma unroll
                for (int j = 0; j < 3; ++j)
                    acc[i][j] += qv[i].x * kv[j].x + qv[i].y * kv[j].y +
                                 qv[i].z * kv[j].z + qv[i].w * kv[j].w;
        }
        __syncthreads();
    }
    const long base = (((long)(m * 16 + b * 4 + h)) * 8 + chunk) * 2304;
    #pragma unroll
    for (int i = 0; i < 3; ++i)
        #pragma unroll
        for (int j = 0; j < 3; ++j)
            part[base + (ty * 3 + i) * 48 + (tx * 3 + j)] = acc[i][j];
}

// ---------------- reduce partials, scale by norms+temperature, softmax ----------------
__global__ __launch_bounds__(256) void reduce_softmax(const float* __restrict__ part,
    const float* __restrict__ invn, const float* __restrict__ temp,
    float* __restrict__ attn)
{
    const int mbh = blockIdx.x;                 // 64
    const int m = mbh >> 4, b = (mbh >> 2) & 3, h = mbh & 3;
    const int qs = (m == 1 || m == 3) ? 1 : 0;
    const int ks = (m == 1 || m == 2) ? 1 : 0;
    __shared__ float sm[48][48];
    const int tid = threadIdx.x;
    const long pbase = (long)mbh * 8 * 2304;
    const float T = temp[h];
    for (int idx = tid; idx < 2304; idx += 256) {
        float v = 0.f;
        #pragma unroll
        for (int c = 0; c < 8; ++c) v += part[pbase + c * 2304 + idx];
        const int d = idx / 48, e = idx % 48;
        const float iq = invn[(qs * 4 + b) * 384 + h * 48 + d];
        const float ik = invn[(ks * 4 + b) * 384 + 192 + h * 48 + e];
        sm[d][e] = v * iq * ik * T;
    }
    __syncthreads();
    if (tid < 48) {
        float mx = -1e30f;
        #pragma unroll
        for (int e = 0; e < 48; ++e) mx = fmaxf(mx, sm[tid][e]);
        float sum = 0.f;
        #pragma unroll
        for (int e = 0; e < 48; ++e) {
            const float v = __expf(sm[tid][e] - mx);
            sm[tid][e] = v;
            sum += v;
        }
        const float inv = 1.f / sum;
        const long abase = (long)mbh * 2304 + (long)tid * 48;
        #pragma unroll
        for (int e = 0; e < 48; ++e) attn[abase + e] = sm[tid][e] * inv;
    }
}

// ---------------- att_out[m][b][h*48+d][n] = sum_e A[d][e] * v[e][n] ----------------
// m==3 (inter_de): reference einsum '...de,bhen->bhdn' SUMS the ellipsis dims,
// so A = sum over all 16 (b,h) of attn_de, applied identically to every (b,h).
__global__ __launch_bounds__(256) void attnv(const float* __restrict__ Z,
    const float* __restrict__ attn, float* __restrict__ AO)
{
    const int nt = blockIdx.x;                  // 16 tiles of 1024 cols
    const int b = blockIdx.y >> 2, h = blockIdx.y & 3;
    const int m = blockIdx.z;
    const int ks = (m == 1 || m == 2) ? 1 : 0;  // v source follows k
    const float* vp = Z + (long)((ks * 4 + b) * C3 + 384 + h * 48) * N_PIX;
    __shared__ float at[48][48];                // transposed: at[e][d]
    const int tid = threadIdx.x;
    if (m == 3) {
        for (int l = tid; l < 2304; l += 256) {
            float s = 0.f;
            #pragma unroll
            for (int bb = 0; bb < 16; ++bb)
                s += attn[(long)(48 + bb) * 2304 + l];
            at[l % 48][l / 48] = s;
        }
    } else {
        const long abase = (long)(m * 16 + b * 4 + h) * 2304;
        for (int l = tid; l < 2304; l += 256)
            at[l % 48][l / 48] = attn[abase + l];
    }
    __syncthreads();
    const int nn = (nt << 10) + (tid << 2);
    float* ao = AO + (long)((m * 4 + b) * CC + h * 48) * N_PIX;
    for (int d0 = 0; d0 < 48; d0 += 8) {
        float4 acc[8] = {};
        for (int e = 0; e < 48; ++e) {
            const float4 v = *(const float4*)(vp + (long)e * N_PIX + nn);
            #pragma unroll
            for (int i = 0; i < 8; ++i) {
                const float w = at[e][d0 + i];
                acc[i].x = fmaf(v.x, w, acc[i].x);
                acc[i].y = fmaf(v.y, w, acc[i].y);
                acc[i].z = fmaf(v.z, w, acc[i].z);
                acc[i].w = fmaf(v.w, w, acc[i].w);
            }
        }
        #pragma unroll
        for (int i = 0; i < 8; ++i)
            *(float4*)(ao + (long)(d0 + i) * N_PIX + nn) = acc[i];
    }
}

extern "C" void kernel_launch(void* const* d_in, const int* in_sizes, int n_in,
                              void* d_out, int out_size, void* d_ws, size_t ws_size,
                              hipStream_t stream)
{
    const float* e     = (const float*)d_in[0];
    const float* d     = (const float*)d_in[1];
    const float* temp  = (const float*)d_in[2];
    const float* w_qkv = (const float*)d_in[3];
    const float* w_dw  = (const float*)d_in[4];
    const float* w_p1  = (const float*)d_in[5];
    const float* w_p2  = (const float*)d_in[6];
    const float* w_p3  = (const float*)d_in[7];
    const float* w_p4  = (const float*)d_in[8];
    float* out = (float*)d_out;
    float* ws  = (float*)d_ws;

    // workspace layout (floats)
    float* z_raw = ws;                      // 2*4*576*16384 = 75,497,472
    float* z     = ws + 75497472L;          // 75,497,472
    float* part  = ws + 150994944L;         // 4*4*4*8*2304 = 1,179,648
    float* attn  = ws + 152174592L;         // 147,456
    float* invn  = ws + 152322048L;         // 3,072
    // total 152,325,120 floats = 609.3 MB

    WPtrs wq; wq.p[0] = w_qkv; wq.p[1] = w_qkv; wq.p[2] = w_qkv; wq.p[3] = w_qkv;
    const long sXin = (long)CC * N_PIX;     // 192*16384
    const long sQKV = (long)C3 * N_PIX;     // 576*16384

    // 1) pointwise qkv GEMM for e (batches 0..3) and d (batches 4..7)
    gemm_mfma<<<dim3(64, 9, 4), 256, 0, stream>>>(wq, 4, e, z_raw, sXin, sQKV);
    gemm_mfma<<<dim3(64, 9, 4), 256, 0, stream>>>(wq, 4, d, z_raw + 4L * sQKV, sXin, sQKV);
    // 2) depthwise 3x3
    dwconv3<<<dim3(2, C3, 8), 256, 0, stream>>>(z_raw, w_dw, z);
    // 3) inverse L2 norms for q,k rows
    rownorm<<<dim3(3072), 256, 0, stream>>>(z, invn);
    // 4) score partials (deterministic two-phase)
    scores_part<<<dim3(8, 16, 4), 256, 0, stream>>>(z, part);
    // 5) reduce + scale + softmax
    reduce_softmax<<<dim3(64), 256, 0, stream>>>(part, invn, temp, attn);
    // 6) attn @ v  (att_out reuses z_raw region)
    float* ao = z_raw;
    attnv<<<dim3(16, 16, 4), 256, 0, stream>>>(z, attn, ao);
    // 7) output projections into d_out
    WPtrs wpj; wpj.p[0] = w_p1; wpj.p[1] = w_p2; wpj.p[2] = w_p3; wpj.p[3] = w_p4;
    gemm_mfma<<<dim3(64, 3, 16), 256, 0, stream>>>(wpj, 4, ao, out, sXin, sXin);
}

// Round 5
// 609.946 us; speedup vs baseline: 2.3740x; 1.4029x over previous
//
#include <hip/hip_runtime.h>

#define N_PIX 16384
#define CC 192
#define C3 576
#define KTOT 192

typedef __bf16 bf16_t;
typedef bf16_t bf16x4 __attribute__((ext_vector_type(4)));
typedef bf16_t bf16x8 __attribute__((ext_vector_type(8)));
typedef float f32x4 __attribute__((ext_vector_type(4)));

struct WPtrs { const float* p[4]; };
struct GArgs { const float* W[16]; long xoff[16]; };

// ---------------- MFMA GEMM body: Y[m][n] = sum_k W[m][k] * X[k][n] ----------
// W row-major stride KTOT=192. fp32 global in/out, bf16 LDS tiles,
// 64m x 256n block tile, K-step 32. A/B fragments use the same k-bijection
// phi(gi,e)=16*(e>>2)+4*gi+(e&3) (A/B layouts are k-symmetric).
__device__ __forceinline__ void gemm_body(const float* __restrict__ W,
    const float* __restrict__ Xb, float* __restrict__ Yb, int m0, int n0)
{
    __shared__ __align__(16) bf16_t Wl[64][36];    // 64 m x 32 k (+pad)
    __shared__ __align__(16) bf16_t Xl[256][36];   // 256 n x 32 k (+pad), transposed
    const int tid = threadIdx.x;
    const int w = tid >> 6;              // wave id: n-offset 64*w
    const int gi = (tid >> 4) & 3;       // lane>>4
    const int li = tid & 15;             // lane&15

    f32x4 acc[4][4];
    #pragma unroll
    for (int i = 0; i < 4; ++i)
        #pragma unroll
        for (int j = 0; j < 4; ++j) acc[i][j] = 0.f;

    const int wm = tid >> 2, wk = (tid & 3) << 3;   // W staging coords

    for (int k0 = 0; k0 < KTOT; k0 += 32) {
        // stage W tile 64x32 (k contiguous per row)
        {
            const float* wp0 = W + (long)(m0 + wm) * KTOT + k0 + wk;
            float4 a = *(const float4*)(wp0);
            float4 b = *(const float4*)(wp0 + 4);
            bf16x4 lo = { (bf16_t)a.x, (bf16_t)a.y, (bf16_t)a.z, (bf16_t)a.w };
            bf16x4 hi = { (bf16_t)b.x, (bf16_t)b.y, (bf16_t)b.z, (bf16_t)b.w };
            *(bf16x4*)&Wl[wm][wk]     = lo;
            *(bf16x4*)&Wl[wm][wk + 4] = hi;
        }
        // stage X tile 32k x 256n, transposed into Xl[n][k]
        {
            const float* xp = Xb + (long)k0 * N_PIX + n0 + tid;   // column tid
            #pragma unroll
            for (int g = 0; g < 8; ++g) {
                float x0 = xp[(long)(4 * g + 0) * N_PIX];
                float x1 = xp[(long)(4 * g + 1) * N_PIX];
                float x2 = xp[(long)(4 * g + 2) * N_PIX];
                float x3 = xp[(long)(4 * g + 3) * N_PIX];
                bf16x4 v = { (bf16_t)x0, (bf16_t)x1, (bf16_t)x2, (bf16_t)x3 };
                *(bf16x4*)&Xl[tid][g * 4] = v;
            }
        }
        __syncthreads();
        bf16x8 af[4], bfr[4];
        #pragma unroll
        for (int mi = 0; mi < 4; ++mi) {
            bf16x4 lo = *(const bf16x4*)&Wl[16 * mi + li][4 * gi];
            bf16x4 hi = *(const bf16x4*)&Wl[16 * mi + li][16 + 4 * gi];
            af[mi] = __builtin_shufflevector(lo, hi, 0, 1, 2, 3, 4, 5, 6, 7);
        }
        #pragma unroll
        for (int ni = 0; ni < 4; ++ni) {
            const int n = 64 * w + 16 * ni + li;
            bf16x4 lo = *(const bf16x4*)&Xl[n][4 * gi];
            bf16x4 hi = *(const bf16x4*)&Xl[n][16 + 4 * gi];
            bfr[ni] = __builtin_shufflevector(lo, hi, 0, 1, 2, 3, 4, 5, 6, 7);
        }
        #pragma unroll
        for (int mi = 0; mi < 4; ++mi)
            #pragma unroll
            for (int ni = 0; ni < 4; ++ni)
                acc[mi][ni] = __builtin_amdgcn_mfma_f32_16x16x32_bf16(
                    af[mi], bfr[ni], acc[mi][ni], 0, 0, 0);
        __syncthreads();
    }
    // epilogue: C/D map col=lane&15, row=4*(lane>>4)+reg  [m89-verified]
    #pragma unroll
    for (int mi = 0; mi < 4; ++mi) {
        #pragma unroll
        for (int ni = 0; ni < 4; ++ni) {
            const int n = n0 + 64 * w + 16 * ni + li;
            #pragma unroll
            for (int r = 0; r < 4; ++r) {
                const int m = m0 + 16 * mi + 4 * gi + r;
                Yb[(long)m * N_PIX + n] = acc[mi][ni][r];
            }
        }
    }
}

__global__ __launch_bounds__(256) void gemm_mfma(GArgs ga,
    const float* __restrict__ X, float* __restrict__ Y, long sY)
{
    const int bt = blockIdx.z;
    gemm_body(ga.W[bt], X + ga.xoff[bt], Y + (long)bt * sY,
              blockIdx.y * 64, blockIdx.x * 256);
}

// ---------------- depthwise 3x3, pad 1 — register-rolling 4x8 strip per thread ----
__global__ __launch_bounds__(256) void dwconv3(const float* __restrict__ Yin,
    const float* __restrict__ wdw, float* __restrict__ Z)
{
    const int sb = blockIdx.z, ch = blockIdx.y;
    const int tid = threadIdx.x;
    const int x0 = (tid & 31) << 2;                         // 0..124
    const int y0 = (blockIdx.x << 6) + ((tid >> 5) << 3);   // strip of 8 rows
    const float* __restrict__ inp = Yin + (long)(sb * C3 + ch) * N_PIX;
    float* __restrict__ outp = Z + (long)(sb * C3 + ch) * N_PIX;
    const float* wch = wdw + ch * 9;
    const float w00 = wch[0], w01 = wch[1], w02 = wch[2];
    const float w10 = wch[3], w11 = wch[4], w12 = wch[5];
    const float w20 = wch[6], w21 = wch[7], w22 = wch[8];
    const bool hasL = (x0 > 0), hasR = (x0 < 124);
    float A[6], B[6], Cr[6];   // [0]=x0-1, [1..4]=x0..x0+3, [5]=x0+4
    auto loadrow = [&](int yy, float* r) {
        if (yy < 0 || yy > 127) {
            r[0] = r[1] = r[2] = r[3] = r[4] = r[5] = 0.f; return;
        }
        const float* p = inp + (yy << 7);
        const float4 v = *(const float4*)(p + x0);
        r[1] = v.x; r[2] = v.y; r[3] = v.z; r[4] = v.w;
        r[0] = hasL ? p[x0 - 1] : 0.f;
        r[5] = hasR ? p[x0 + 4] : 0.f;
    };
    loadrow(y0 - 1, A);
    loadrow(y0,     B);
    #pragma unroll
    for (int r = 0; r < 8; ++r) {
        loadrow(y0 + r + 1, Cr);
        float o[4];
        #pragma unroll
        for (int i = 0; i < 4; ++i) {
            float s;
            s = fmaf(w00, A[i],  fmaf(w01, A[i + 1],  w02 * A[i + 2]));
            s = fmaf(w10, B[i],  fmaf(w11, B[i + 1],  fmaf(w12, B[i + 2], s)));
            s = fmaf(w20, Cr[i], fmaf(w21, Cr[i + 1], fmaf(w22, Cr[i + 2], s)));
            o[i] = s;
        }
        *(float4*)(outp + ((y0 + r) << 7) + x0) = make_float4(o[0], o[1], o[2], o[3]);
        #pragma unroll
        for (int i = 0; i < 6; ++i) { A[i] = B[i]; B[i] = Cr[i]; }
    }
}

// ---------------- row inverse L2 norms for q,k ----------------
__global__ __launch_bounds__(256) void rownorm(const float* __restrict__ Z,
                                               float* __restrict__ invn)
{
    const int row = blockIdx.x;             // [0, 2*4*384)
    const int s = row / 1536;
    const int b = (row / 384) & 3;
    const int cc = row % 384;               // 0..191 q, 192..383 k
    const float* p = Z + (long)((s * 4 + b) * C3 + cc) * N_PIX;
    const int tid = threadIdx.x;
    float ss = 0.f;
    for (int i = tid * 4; i < N_PIX; i += 1024) {
        float4 v = *(const float4*)(p + i);
        ss += v.x * v.x + v.y * v.y + v.z * v.z + v.w * v.w;
    }
    #pragma unroll
    for (int off = 32; off > 0; off >>= 1) ss += __shfl_down(ss, off);
    __shared__ float red[4];
    if ((tid & 63) == 0) red[tid >> 6] = ss;
    __syncthreads();
    if (tid == 0) {
        float t = red[0] + red[1] + red[2] + red[3];
        invn[row] = 1.f / fmaxf(sqrtf(t), 1e-12f);
    }
}

// ---------------- raw score partials: part[m][b][h][chunk][48][48] ----------------
__global__ __launch_bounds__(256) void scores_part(const float* __restrict__ Z,
                                                   float* __restrict__ part)
{
    const int chunk = blockIdx.x;                    // 8 chunks of 2048
    const int b = blockIdx.y >> 2, h = blockIdx.y & 3;
    const int m = blockIdx.z;                        // combo
    const int qs = (m == 1 || m == 3) ? 1 : 0;
    const int ks = (m == 1 || m == 2) ? 1 : 0;
    const float* qp = Z + (long)((qs * 4 + b) * C3 + h * 48) * N_PIX;
    const float* kp = Z + (long)((ks * 4 + b) * C3 + 192 + h * 48) * N_PIX;
    __shared__ float qsm[48][132];
    __shared__ float ksm[48][132];
    const int tid = threadIdx.x;
    const int ty = tid >> 4, tx = tid & 15;
    float acc[3][3] = {};
    const int nbase = chunk * 2048;
    for (int nb = 0; nb < 2048; nb += 128) {
        for (int l = tid; l < 48 * 32; l += 256) {
            const int r = l >> 5, c = (l & 31) << 2;
            *(float4*)(&qsm[r][c]) = *(const float4*)(qp + (long)r * N_PIX + nbase + nb + c);
            *(float4*)(&ksm[r][c]) = *(const float4*)(kp + (long)r * N_PIX + nbase + nb + c);
        }
        __syncthreads();
        #pragma unroll 4
        for (int nn = 0; nn < 128; nn += 4) {
            float4 qv[3], kv[3];
            #pragma unroll
            for (int i = 0; i < 3; ++i) qv[i] = *(const float4*)(&qsm[ty * 3 + i][nn]);
            #pragma unroll
            for (int j = 0; j < 3; ++j) kv[j] = *(const float4*)(&ksm[tx * 3 + j][nn]);
            #pragma unroll
            for (int i = 0; i < 3; ++i)
                #pragma unroll
                for (int j = 0; j < 3; ++j)
                    acc[i][j] += qv[i].x * kv[j].x + qv[i].y * kv[j].y +
                                 qv[i].z * kv[j].z + qv[i].w * kv[j].w;
        }
        __syncthreads();
    }
    const long base = (((long)(m * 16 + b * 4 + h)) * 8 + chunk) * 2304;
    #pragma unroll
    for (int i = 0; i < 3; ++i)
        #pragma unroll
        for (int j = 0; j < 3; ++j)
            part[base + (ty * 3 + i) * 48 + (tx * 3 + j)] = acc[i][j];
}

// ---------------- reduce partials, scale by norms+temperature, softmax ----------------
__global__ __launch_bounds__(256) void reduce_softmax(const float* __restrict__ part,
    const float* __restrict__ invn, const float* __restrict__ temp,
    float* __restrict__ attn)
{
    const int mbh = blockIdx.x;                 // 64
    const int m = mbh >> 4, b = (mbh >> 2) & 3, h = mbh & 3;
    const int qs = (m == 1 || m == 3) ? 1 : 0;
    const int ks = (m == 1 || m == 2) ? 1 : 0;
    __shared__ float sm[48][48];
    const int tid = threadIdx.x;
    const long pbase = (long)mbh * 8 * 2304;
    const float T = temp[h];
    for (int idx = tid; idx < 2304; idx += 256) {
        float v = 0.f;
        #pragma unroll
        for (int c = 0; c < 8; ++c) v += part[pbase + c * 2304 + idx];
        const int d = idx / 48, e = idx % 48;
        const float iq = invn[(qs * 4 + b) * 384 + h * 48 + d];
        const float ik = invn[(ks * 4 + b) * 384 + 192 + h * 48 + e];
        sm[d][e] = v * iq * ik * T;
    }
    __syncthreads();
    if (tid < 48) {
        float mx = -1e30f;
        #pragma unroll
        for (int e = 0; e < 48; ++e) mx = fmaxf(mx, sm[tid][e]);
        float sum = 0.f;
        #pragma unroll
        for (int e = 0; e < 48; ++e) {
            const float v = __expf(sm[tid][e] - mx);
            sm[tid][e] = v;
            sum += v;
        }
        const float inv = 1.f / sum;
        const long abase = (long)mbh * 2304 + (long)tid * 48;
        #pragma unroll
        for (int e = 0; e < 48; ++e) attn[abase + e] = sm[tid][e] * inv;
    }
}

// ---------------- fold attn into projection: M[m][b][o][h*48+e] ----------------
// M = w_p[m][o, h*48+d] * A[m,b,h][d][e] summed over d.
// m==3 (inter_de): reference einsum '...de,bhen->bhdn' SUMS the ellipsis dims,
// so A := sum over all 16 (b,h) of attn_de, same for every (b,h).
__global__ __launch_bounds__(256) void make_M(const float* __restrict__ attn,
                                              WPtrs wp, float* __restrict__ M)
{
    const int h = blockIdx.x & 3;
    const int b = (blockIdx.x >> 2) & 3;
    const int m = blockIdx.x >> 4;              // grid 64
    __shared__ float A[48][48];
    const int tid = threadIdx.x;
    if (m == 3) {
        for (int l = tid; l < 2304; l += 256) {
            float s = 0.f;
            #pragma unroll
            for (int bb = 0; bb < 16; ++bb)
                s += attn[(long)(48 + bb) * 2304 + l];
            A[l / 48][l % 48] = s;
        }
    } else {
        const long ab = (long)(m * 16 + b * 4 + h) * 2304;
        for (int l = tid; l < 2304; l += 256)
            A[l / 48][l % 48] = attn[ab + l];
    }
    __syncthreads();
    const float* W = wp.p[m];
    float* Mo = M + (long)(m * 4 + b) * 192 * 192;
    for (int o = tid >> 4; o < 192; o += 16) {
        const float* wrow = W + (long)o * 192 + h * 48;
        for (int e2 = tid & 15; e2 < 48; e2 += 16) {
            float s = 0.f;
            #pragma unroll
            for (int d = 0; d < 48; ++d) s = fmaf(wrow[d], A[d][e2], s);
            Mo[(long)o * 192 + h * 48 + e2] = s;
        }
    }
}

extern "C" void kernel_launch(void* const* d_in, const int* in_sizes, int n_in,
                              void* d_out, int out_size, void* d_ws, size_t ws_size,
                              hipStream_t stream)
{
    const float* e     = (const float*)d_in[0];
    const float* d     = (const float*)d_in[1];
    const float* temp  = (const float*)d_in[2];
    const float* w_qkv = (const float*)d_in[3];
    const float* w_dw  = (const float*)d_in[4];
    const float* w_p1  = (const float*)d_in[5];
    const float* w_p2  = (const float*)d_in[6];
    const float* w_p3  = (const float*)d_in[7];
    const float* w_p4  = (const float*)d_in[8];
    float* out = (float*)d_out;
    float* ws  = (float*)d_ws;

    // workspace layout (floats)
    float* z_raw = ws;                      // 2*4*576*16384 = 75,497,472  (later reused for M)
    float* z     = ws + 75497472L;          // 75,497,472
    float* part  = ws + 150994944L;         // 4*4*4*8*2304 = 1,179,648
    float* attn  = ws + 152174592L;         // 147,456
    float* invn  = ws + 152322048L;         // 3,072
    // total 152,325,120 floats = 609.3 MB

    const long sXin = (long)CC * N_PIX;     // 192*16384
    const long sQKV = (long)C3 * N_PIX;     // 576*16384

    // 1) pointwise qkv GEMM for e (batches 0..3) and d (batches 4..7)
    GArgs gq{};
    for (int bt = 0; bt < 16; ++bt) { gq.W[bt] = w_qkv; gq.xoff[bt] = (long)(bt & 3) * sXin; }
    gemm_mfma<<<dim3(64, 9, 4), 256, 0, stream>>>(gq, e, z_raw, sQKV);
    gemm_mfma<<<dim3(64, 9, 4), 256, 0, stream>>>(gq, d, z_raw + 4L * sQKV, sQKV);
    // 2) depthwise 3x3
    dwconv3<<<dim3(2, C3, 8), 256, 0, stream>>>(z_raw, w_dw, z);
    // 3) inverse L2 norms for q,k rows
    rownorm<<<dim3(3072), 256, 0, stream>>>(z, invn);
    // 4) score partials (deterministic two-phase)
    scores_part<<<dim3(8, 16, 4), 256, 0, stream>>>(z, part);
    // 5) reduce + scale + softmax
    reduce_softmax<<<dim3(64), 256, 0, stream>>>(part, invn, temp, attn);
    // 6) fold attn into projection matrices (M lives in the dead z_raw region)
    float* Mmat = z_raw;
    WPtrs wpj; wpj.p[0] = w_p1; wpj.p[1] = w_p2; wpj.p[2] = w_p3; wpj.p[3] = w_p4;
    make_M<<<dim3(64), 256, 0, stream>>>(attn, wpj, Mmat);
    // 7) fused (proj ∘ attn) @ V directly into d_out
    GArgs gm{};
    for (int bt = 0; bt < 16; ++bt) {
        const int m = bt >> 2, b = bt & 3;
        const int ks = (m == 1 || m == 2) ? 1 : 0;
        gm.W[bt] = Mmat + (long)bt * 192 * 192;
        gm.xoff[bt] = ((long)((ks * 4 + b) * C3 + 384)) * N_PIX;
    }
    gemm_mfma<<<dim3(64, 3, 16), 256, 0, stream>>>(gm, z, out, sXin);
}

// Round 6
// 562.418 us; speedup vs baseline: 2.5747x; 1.0845x over previous
//
#include <hip/hip_runtime.h>

#define N_PIX 16384
#define CC 192
#define C3 576
#define KTOT 192
#define NCH 32
#define CHUNK 512

typedef __bf16 bf16_t;
typedef bf16_t bf16x4 __attribute__((ext_vector_type(4)));
typedef bf16_t bf16x8 __attribute__((ext_vector_type(8)));
typedef float f32x4 __attribute__((ext_vector_type(4)));

struct WPtrs { const float* p[4]; };
struct GArgs { const float* W[16]; long xoff[16]; };

// ---------------- MFMA GEMM (f32 X): Y[m][n] = sum_k W[m][k] * X[k][n] -------
// 64m x 256n tile, K-step 32. A/B frags share k-bijection phi(gi,e)=
// 16*(e>>2)+4*gi+(e&3); C/D map col=lane&15, row=4*(lane>>4)+reg [m89].
__global__ __launch_bounds__(256) void gemm_mfma(GArgs ga,
    const float* __restrict__ X, float* __restrict__ Y, long sY)
{
    __shared__ __align__(16) bf16_t Wl[64][36];
    __shared__ __align__(16) bf16_t Xl[256][36];
    const int bt = blockIdx.z;
    const float* __restrict__ W = ga.W[bt];
    const float* __restrict__ Xb = X + ga.xoff[bt];
    float* __restrict__ Yb = Y + (long)bt * sY;
    const int m0 = blockIdx.y * 64, n0 = blockIdx.x * 256;
    const int tid = threadIdx.x;
    const int w = tid >> 6;
    const int gi = (tid >> 4) & 3;
    const int li = tid & 15;

    f32x4 acc[4][4];
    #pragma unroll
    for (int i = 0; i < 4; ++i)
        #pragma unroll
        for (int j = 0; j < 4; ++j) acc[i][j] = 0.f;

    const int wm = tid >> 2, wk = (tid & 3) << 3;

    for (int k0 = 0; k0 < KTOT; k0 += 32) {
        {
            const float* wp0 = W + (long)(m0 + wm) * KTOT + k0 + wk;
            float4 a = *(const float4*)(wp0);
            float4 b = *(const float4*)(wp0 + 4);
            bf16x4 lo = { (bf16_t)a.x, (bf16_t)a.y, (bf16_t)a.z, (bf16_t)a.w };
            bf16x4 hi = { (bf16_t)b.x, (bf16_t)b.y, (bf16_t)b.z, (bf16_t)b.w };
            *(bf16x4*)&Wl[wm][wk]     = lo;
            *(bf16x4*)&Wl[wm][wk + 4] = hi;
        }
        {
            const float* xp = Xb + (long)k0 * N_PIX + n0 + tid;
            #pragma unroll
            for (int g = 0; g < 8; ++g) {
                float x0 = xp[(long)(4 * g + 0) * N_PIX];
                float x1 = xp[(long)(4 * g + 1) * N_PIX];
                float x2 = xp[(long)(4 * g + 2) * N_PIX];
                float x3 = xp[(long)(4 * g + 3) * N_PIX];
                bf16x4 v = { (bf16_t)x0, (bf16_t)x1, (bf16_t)x2, (bf16_t)x3 };
                *(bf16x4*)&Xl[tid][g * 4] = v;
            }
        }
        __syncthreads();
        bf16x8 af[4], bfr[4];
        #pragma unroll
        for (int mi = 0; mi < 4; ++mi) {
            bf16x4 lo = *(const bf16x4*)&Wl[16 * mi + li][4 * gi];
            bf16x4 hi = *(const bf16x4*)&Wl[16 * mi + li][16 + 4 * gi];
            af[mi] = __builtin_shufflevector(lo, hi, 0, 1, 2, 3, 4, 5, 6, 7);
        }
        #pragma unroll
        for (int ni = 0; ni < 4; ++ni) {
            const int n = 64 * w + 16 * ni + li;
            bf16x4 lo = *(const bf16x4*)&Xl[n][4 * gi];
            bf16x4 hi = *(const bf16x4*)&Xl[n][16 + 4 * gi];
            bfr[ni] = __builtin_shufflevector(lo, hi, 0, 1, 2, 3, 4, 5, 6, 7);
        }
        #pragma unroll
        for (int mi = 0; mi < 4; ++mi)
            #pragma unroll
            for (int ni = 0; ni < 4; ++ni)
                acc[mi][ni] = __builtin_amdgcn_mfma_f32_16x16x32_bf16(
                    af[mi], bfr[ni], acc[mi][ni], 0, 0, 0);
        __syncthreads();
    }
    #pragma unroll
    for (int mi = 0; mi < 4; ++mi)
        #pragma unroll
        for (int ni = 0; ni < 4; ++ni) {
            const int n = n0 + 64 * w + 16 * ni + li;
            #pragma unroll
            for (int r = 0; r < 4; ++r) {
                const int m = m0 + 16 * mi + 4 * gi + r;
                Yb[(long)m * N_PIX + n] = acc[mi][ni][r];
            }
        }
}

// ---------------- MFMA GEMM (bf16 X) — same structure, X already bf16 -------
__global__ __launch_bounds__(256) void gemm_mfma_bx(GArgs ga,
    const bf16_t* __restrict__ X, float* __restrict__ Y, long sY)
{
    __shared__ __align__(16) bf16_t Wl[64][36];
    __shared__ __align__(16) bf16_t Xl[256][36];
    const int bt = blockIdx.z;
    const float* __restrict__ W = ga.W[bt];
    const bf16_t* __restrict__ Xb = X + ga.xoff[bt];
    float* __restrict__ Yb = Y + (long)bt * sY;
    const int m0 = blockIdx.y * 64, n0 = blockIdx.x * 256;
    const int tid = threadIdx.x;
    const int w = tid >> 6;
    const int gi = (tid >> 4) & 3;
    const int li = tid & 15;

    f32x4 acc[4][4];
    #pragma unroll
    for (int i = 0; i < 4; ++i)
        #pragma unroll
        for (int j = 0; j < 4; ++j) acc[i][j] = 0.f;

    const int wm = tid >> 2, wk = (tid & 3) << 3;

    for (int k0 = 0; k0 < KTOT; k0 += 32) {
        {
            const float* wp0 = W + (long)(m0 + wm) * KTOT + k0 + wk;
            float4 a = *(const float4*)(wp0);
            float4 b = *(const float4*)(wp0 + 4);
            bf16x4 lo = { (bf16_t)a.x, (bf16_t)a.y, (bf16_t)a.z, (bf16_t)a.w };
            bf16x4 hi = { (bf16_t)b.x, (bf16_t)b.y, (bf16_t)b.z, (bf16_t)b.w };
            *(bf16x4*)&Wl[wm][wk]     = lo;
            *(bf16x4*)&Wl[wm][wk + 4] = hi;
        }
        {
            const bf16_t* xp = Xb + (long)k0 * N_PIX + n0 + tid;
            #pragma unroll
            for (int g = 0; g < 8; ++g) {
                bf16x4 v = { xp[(long)(4 * g + 0) * N_PIX],
                             xp[(long)(4 * g + 1) * N_PIX],
                             xp[(long)(4 * g + 2) * N_PIX],
                             xp[(long)(4 * g + 3) * N_PIX] };
                *(bf16x4*)&Xl[tid][g * 4] = v;
            }
        }
        __syncthreads();
        bf16x8 af[4], bfr[4];
        #pragma unroll
        for (int mi = 0; mi < 4; ++mi) {
            bf16x4 lo = *(const bf16x4*)&Wl[16 * mi + li][4 * gi];
            bf16x4 hi = *(const bf16x4*)&Wl[16 * mi + li][16 + 4 * gi];
            af[mi] = __builtin_shufflevector(lo, hi, 0, 1, 2, 3, 4, 5, 6, 7);
        }
        #pragma unroll
        for (int ni = 0; ni < 4; ++ni) {
            const int n = 64 * w + 16 * ni + li;
            bf16x4 lo = *(const bf16x4*)&Xl[n][4 * gi];
            bf16x4 hi = *(const bf16x4*)&Xl[n][16 + 4 * gi];
            bfr[ni] = __builtin_shufflevector(lo, hi, 0, 1, 2, 3, 4, 5, 6, 7);
        }
        #pragma unroll
        for (int mi = 0; mi < 4; ++mi)
            #pragma unroll
            for (int ni = 0; ni < 4; ++ni)
                acc[mi][ni] = __builtin_amdgcn_mfma_f32_16x16x32_bf16(
                    af[mi], bfr[ni], acc[mi][ni], 0, 0, 0);
        __syncthreads();
    }
    #pragma unroll
    for (int mi = 0; mi < 4; ++mi)
        #pragma unroll
        for (int ni = 0; ni < 4; ++ni) {
            const int n = n0 + 64 * w + 16 * ni + li;
            #pragma unroll
            for (int r = 0; r < 4; ++r) {
                const int m = m0 + 16 * mi + 4 * gi + r;
                Yb[(long)m * N_PIX + n] = acc[mi][ni][r];
            }
        }
}

// ---------------- depthwise 3x3, pad 1 — bf16 output ----------------
__global__ __launch_bounds__(256) void dwconv3(const float* __restrict__ Yin,
    const float* __restrict__ wdw, bf16_t* __restrict__ Z)
{
    const int sb = blockIdx.z, ch = blockIdx.y;
    const int tid = threadIdx.x;
    const int x0 = (tid & 31) << 2;
    const int y0 = (blockIdx.x << 6) + ((tid >> 5) << 3);
    const float* __restrict__ inp = Yin + (long)(sb * C3 + ch) * N_PIX;
    bf16_t* __restrict__ outp = Z + (long)(sb * C3 + ch) * N_PIX;
    const float* wch = wdw + ch * 9;
    const float w00 = wch[0], w01 = wch[1], w02 = wch[2];
    const float w10 = wch[3], w11 = wch[4], w12 = wch[5];
    const float w20 = wch[6], w21 = wch[7], w22 = wch[8];
    const bool hasL = (x0 > 0), hasR = (x0 < 124);
    float A[6], B[6], Cr[6];
    auto loadrow = [&](int yy, float* r) {
        if (yy < 0 || yy > 127) {
            r[0] = r[1] = r[2] = r[3] = r[4] = r[5] = 0.f; return;
        }
        const float* p = inp + (yy << 7);
        const float4 v = *(const float4*)(p + x0);
        r[1] = v.x; r[2] = v.y; r[3] = v.z; r[4] = v.w;
        r[0] = hasL ? p[x0 - 1] : 0.f;
        r[5] = hasR ? p[x0 + 4] : 0.f;
    };
    loadrow(y0 - 1, A);
    loadrow(y0,     B);
    #pragma unroll
    for (int r = 0; r < 8; ++r) {
        loadrow(y0 + r + 1, Cr);
        float o[4];
        #pragma unroll
        for (int i = 0; i < 4; ++i) {
            float s;
            s = fmaf(w00, A[i],  fmaf(w01, A[i + 1],  w02 * A[i + 2]));
            s = fmaf(w10, B[i],  fmaf(w11, B[i + 1],  fmaf(w12, B[i + 2], s)));
            s = fmaf(w20, Cr[i], fmaf(w21, Cr[i + 1], fmaf(w22, Cr[i + 2], s)));
            o[i] = s;
        }
        bf16x4 ov = { (bf16_t)o[0], (bf16_t)o[1], (bf16_t)o[2], (bf16_t)o[3] };
        *(bf16x4*)(outp + ((y0 + r) << 7) + x0) = ov;
        #pragma unroll
        for (int i = 0; i < 6; ++i) { A[i] = B[i]; B[i] = Cr[i]; }
    }
}

// ---------------- row inverse L2 norms for q,k (bf16 input) ----------------
__global__ __launch_bounds__(256) void rownorm(const bf16_t* __restrict__ Z,
                                               float* __restrict__ invn)
{
    const int row = blockIdx.x;             // [0, 2*4*384)
    const int s = row / 1536;
    const int b = (row / 384) & 3;
    const int cc = row % 384;
    const bf16_t* p = Z + (long)((s * 4 + b) * C3 + cc) * N_PIX;
    const int tid = threadIdx.x;
    float ss = 0.f;
    for (int i = tid * 8; i < N_PIX; i += 2048) {
        bf16x8 v = *(const bf16x8*)(p + i);
        #pragma unroll
        for (int j = 0; j < 8; ++j) {
            const float f = (float)v[j];
            ss = fmaf(f, f, ss);
        }
    }
    #pragma unroll
    for (int off = 32; off > 0; off >>= 1) ss += __shfl_down(ss, off);
    __shared__ float red[4];
    if ((tid & 63) == 0) red[tid >> 6] = ss;
    __syncthreads();
    if (tid == 0) {
        float t = red[0] + red[1] + red[2] + red[3];
        invn[row] = 1.f / fmaxf(sqrtf(t), 1e-12f);
    }
}

// ---------------- MFMA score partials: all 4 combos share one LDS stage ------
// block = (chunk, b*4+h); wave m = combo (ee, dd, ed, de).
// part[((m*16+bh)*NCH + c)*2304 + d*48 + e]
__global__ __launch_bounds__(256) void scores_mfma(const bf16_t* __restrict__ Z,
                                                   float* __restrict__ part)
{
    const int c = blockIdx.x;
    const int bh = blockIdx.y;
    const int b = bh >> 2, h = bh & 3;
    __shared__ __align__(16) bf16_t T[4][48][72];   // qe, qd, ke, kd
    const int tid = threadIdx.x;
    const int m = tid >> 6;
    const int gi = (tid >> 4) & 3, li = tid & 15;
    const int qs = (m == 1 || m == 3) ? 1 : 0;
    const int ks = (m == 1 || m == 2) ? 1 : 0;
    f32x4 acc[3][3];
    #pragma unroll
    for (int i = 0; i < 3; ++i)
        #pragma unroll
        for (int j = 0; j < 3; ++j) acc[i][j] = 0.f;

    const int nbase = c * CHUNK;
    // staging coords: l -> tensor t, row r, 8-elem segment s
    for (int k0 = 0; k0 < CHUNK; k0 += 64) {
        __syncthreads();
        for (int l = tid; l < 1536; l += 256) {
            const int t = l / 384;
            const int rem = l - t * 384;
            const int r = rem >> 3, s = rem & 7;
            const int src = t & 1 ? 0 : 0;      // placeholder (see below)
            const int sidx = (t < 2) ? t : (t - 2);
            const int qk = (t < 2) ? 0 : 1;
            const bf16_t* gp = Z + ((long)((sidx * 4 + b) * C3 + qk * 192 + h * 48 + r)) * N_PIX
                                 + nbase + k0 + s * 8;
            *(bf16x8*)&T[t][r][s * 8] = *(const bf16x8*)gp;
            (void)src;
        }
        __syncthreads();
        #pragma unroll
        for (int k2 = 0; k2 < 64; k2 += 32) {
            bf16x8 af[3], bfr[3];
            #pragma unroll
            for (int i = 0; i < 3; ++i) {
                bf16x4 lo = *(const bf16x4*)&T[qs][16 * i + li][k2 + 4 * gi];
                bf16x4 hi = *(const bf16x4*)&T[qs][16 * i + li][k2 + 16 + 4 * gi];
                af[i] = __builtin_shufflevector(lo, hi, 0, 1, 2, 3, 4, 5, 6, 7);
            }
            #pragma unroll
            for (int j = 0; j < 3; ++j) {
                bf16x4 lo = *(const bf16x4*)&T[2 + ks][16 * j + li][k2 + 4 * gi];
                bf16x4 hi = *(const bf16x4*)&T[2 + ks][16 * j + li][k2 + 16 + 4 * gi];
                bfr[j] = __builtin_shufflevector(lo, hi, 0, 1, 2, 3, 4, 5, 6, 7);
            }
            #pragma unroll
            for (int i = 0; i < 3; ++i)
                #pragma unroll
                for (int j = 0; j < 3; ++j)
                    acc[i][j] = __builtin_amdgcn_mfma_f32_16x16x32_bf16(
                        af[i], bfr[j], acc[i][j], 0, 0, 0);
        }
    }
    const long base = ((long)(m * 16 + bh) * NCH + c) * 2304;
    #pragma unroll
    for (int i = 0; i < 3; ++i)
        #pragma unroll
        for (int j = 0; j < 3; ++j) {
            const int e = 16 * j + li;
            #pragma unroll
            for (int r = 0; r < 4; ++r) {
                const int d = 16 * i + 4 * gi + r;
                part[base + d * 48 + e] = acc[i][j][r];
            }
        }
}

// ---------------- reduce partials, scale by norms+temperature, softmax -------
__global__ __launch_bounds__(256) void reduce_softmax(const float* __restrict__ part,
    const float* __restrict__ invn, const float* __restrict__ temp,
    float* __restrict__ attn)
{
    const int mbh = blockIdx.x;                 // 64
    const int m = mbh >> 4, b = (mbh >> 2) & 3, h = mbh & 3;
    const int qs = (m == 1 || m == 3) ? 1 : 0;
    const int ks = (m == 1 || m == 2) ? 1 : 0;
    __shared__ float sm[48][48];
    const int tid = threadIdx.x;
    const long pbase = (long)mbh * NCH * 2304;
    const float T = temp[h];
    for (int idx = tid; idx < 2304; idx += 256) {
        float v = 0.f;
        #pragma unroll 8
        for (int c = 0; c < NCH; ++c) v += part[pbase + c * 2304 + idx];
        const int d = idx / 48, e = idx % 48;
        const float iq = invn[(qs * 4 + b) * 384 + h * 48 + d];
        const float ik = invn[(ks * 4 + b) * 384 + 192 + h * 48 + e];
        sm[d][e] = v * iq * ik * T;
    }
    __syncthreads();
    if (tid < 48) {
        float mx = -1e30f;
        #pragma unroll
        for (int e = 0; e < 48; ++e) mx = fmaxf(mx, sm[tid][e]);
        float sum = 0.f;
        #pragma unroll
        for (int e = 0; e < 48; ++e) {
            const float v = __expf(sm[tid][e] - mx);
            sm[tid][e] = v;
            sum += v;
        }
        const float inv = 1.f / sum;
        const long abase = (long)mbh * 2304 + (long)tid * 48;
        #pragma unroll
        for (int e = 0; e < 48; ++e) attn[abase + e] = sm[tid][e] * inv;
    }
}

// ---------------- fold attn into projection: M[m][b][o][h*48+e] ----------------
// m==3 (inter_de): einsum '...de,bhen->bhdn' SUMS the ellipsis dims.
__global__ __launch_bounds__(256) void make_M(const float* __restrict__ attn,
                                              WPtrs wp, float* __restrict__ M)
{
    const int h = blockIdx.x & 3;
    const int b = (blockIdx.x >> 2) & 3;
    const int m = blockIdx.x >> 4;              // grid 64
    __shared__ float A[48][48];
    const int tid = threadIdx.x;
    if (m == 3) {
        for (int l = tid; l < 2304; l += 256) {
            float s = 0.f;
            #pragma unroll
            for (int bb = 0; bb < 16; ++bb)
                s += attn[(long)(48 + bb) * 2304 + l];
            A[l / 48][l % 48] = s;
        }
    } else {
        const long ab = (long)(m * 16 + b * 4 + h) * 2304;
        for (int l = tid; l < 2304; l += 256)
            A[l / 48][l % 48] = attn[ab + l];
    }
    __syncthreads();
    const float* W = wp.p[m];
    float* Mo = M + (long)(m * 4 + b) * 192 * 192;
    for (int o = tid >> 4; o < 192; o += 16) {
        const float* wrow = W + (long)o * 192 + h * 48;
        for (int e2 = tid & 15; e2 < 48; e2 += 16) {
            float s = 0.f;
            #pragma unroll
            for (int d = 0; d < 48; ++d) s = fmaf(wrow[d], A[d][e2], s);
            Mo[(long)o * 192 + h * 48 + e2] = s;
        }
    }
}

extern "C" void kernel_launch(void* const* d_in, const int* in_sizes, int n_in,
                              void* d_out, int out_size, void* d_ws, size_t ws_size,
                              hipStream_t stream)
{
    const float* e     = (const float*)d_in[0];
    const float* d     = (const float*)d_in[1];
    const float* temp  = (const float*)d_in[2];
    const float* w_qkv = (const float*)d_in[3];
    const float* w_dw  = (const float*)d_in[4];
    const float* w_p1  = (const float*)d_in[5];
    const float* w_p2  = (const float*)d_in[6];
    const float* w_p3  = (const float*)d_in[7];
    const float* w_p4  = (const float*)d_in[8];
    float* out = (float*)d_out;
    float* ws  = (float*)d_ws;

    // workspace layout (floats)
    float* z_raw = ws;                      // 75,497,472 f32 (qkv raw; later part+M)
    bf16_t* zb   = (bf16_t*)(ws + 75497472L);  // bf16 z, 150,994,944 bf16 = 75,497,472 f32 region (half used)
    float* attn  = ws + 152174592L;         // 147,456
    float* invn  = ws + 152322048L;         // 3,072

    const long sXin = (long)CC * N_PIX;
    const long sQKV = (long)C3 * N_PIX;

    // 1) pointwise qkv GEMM for e (batches 0..3) and d (batches 4..7), f32 out
    GArgs gq{};
    for (int bt = 0; bt < 16; ++bt) { gq.W[bt] = w_qkv; gq.xoff[bt] = (long)(bt & 3) * sXin; }
    gemm_mfma<<<dim3(64, 9, 4), 256, 0, stream>>>(gq, e, z_raw, sQKV);
    gemm_mfma<<<dim3(64, 9, 4), 256, 0, stream>>>(gq, d, z_raw + 4L * sQKV, sQKV);
    // 2) depthwise 3x3 -> bf16 z
    dwconv3<<<dim3(2, C3, 8), 256, 0, stream>>>(z_raw, w_dw, zb);
    // 3) inverse L2 norms for q,k rows (bf16 input)
    rownorm<<<dim3(3072), 256, 0, stream>>>(zb, invn);
    // 4) MFMA score partials, 4 combos fused (part reuses dead z_raw region)
    float* part = z_raw;                    // 4*16*NCH*2304 = 4,718,592 f32
    scores_mfma<<<dim3(NCH, 16), 256, 0, stream>>>(zb, part);
    // 5) reduce + scale + softmax
    reduce_softmax<<<dim3(64), 256, 0, stream>>>(part, invn, temp, attn);
    // 6) fold attn into projection matrices
    float* Mmat = z_raw + 8388608L;         // 589,824 f32, disjoint from part
    WPtrs wpj; wpj.p[0] = w_p1; wpj.p[1] = w_p2; wpj.p[2] = w_p3; wpj.p[3] = w_p4;
    make_M<<<dim3(64), 256, 0, stream>>>(attn, wpj, Mmat);
    // 7) fused (proj ∘ attn) @ V directly into d_out (V is bf16)
    GArgs gm{};
    for (int bt = 0; bt < 16; ++bt) {
        const int m = bt >> 2, b = bt & 3;
        const int ks = (m == 1 || m == 2) ? 1 : 0;
        gm.W[bt] = Mmat + (long)bt * 192 * 192;
        gm.xoff[bt] = ((long)((ks * 4 + b) * C3 + 384)) * N_PIX;
    }
    gemm_mfma_bx<<<dim3(64, 3, 16), 256, 0, stream>>>(gm, zb, out, sXin);
}

// Round 7
// 384.683 us; speedup vs baseline: 3.7642x; 1.4620x over previous
//
#include <hip/hip_runtime.h>

#define N_PIX 16384
#define CC 192
#define C3 576
#define KTOT 192
#define NCH 32
#define CHUNK 512

typedef __bf16 bf16_t;
typedef bf16_t bf16x4 __attribute__((ext_vector_type(4)));
typedef bf16_t bf16x8 __attribute__((ext_vector_type(8)));
typedef float f32x4 __attribute__((ext_vector_type(4)));

struct WPtrs { const float* p[4]; };
struct GArgs { const float* W[16]; long xoff[16]; };

// ---------------- MFMA GEMM: Y[m][n] = sum_k W[m][k] * X[k][n], K=192 --------
// 64m x 256n tile. W (f32, row-major stride 192) staged to LDS ONCE for all K.
// X staged per 32-k tile via register prefetch (T14 split: issue loads for
// tile t+1 before computing tile t). A/B frags share k-bijection
// phi(gi,e)=16*(e>>2)+4*gi+(e&3); C/D map col=lane&15, row=4*(lane>>4)+reg.
template <typename XT, typename YT>
__global__ __launch_bounds__(256) void gemm_k192(GArgs ga,
    const XT* __restrict__ X, YT* __restrict__ Y, long sY)
{
    __shared__ __align__(16) bf16_t Wl[64][200];   // 64m x 192k (+8 pad)
    __shared__ __align__(16) bf16_t Xl[256][36];   // 256n x 32k (+4 pad)
    const int bt = blockIdx.z;
    const float* __restrict__ W = ga.W[bt];
    const XT* __restrict__ Xb = X + ga.xoff[bt];
    YT* __restrict__ Yb = Y + (long)bt * sY;
    const int m0 = blockIdx.y * 64, n0 = blockIdx.x * 256;
    const int tid = threadIdx.x;
    const int w = tid >> 6;
    const int gi = (tid >> 4) & 3;
    const int li = tid & 15;

    // stage all of W: 4 threads/row, each 48 k = 6 bf16x8 segments
    {
        const int wr = tid >> 2, wkb = (tid & 3) * 48;
        #pragma unroll
        for (int j = 0; j < 6; ++j) {
            const float* wp0 = W + (long)(m0 + wr) * KTOT + wkb + 8 * j;
            float4 a = *(const float4*)(wp0);
            float4 b = *(const float4*)(wp0 + 4);
            bf16x8 v = { (bf16_t)a.x, (bf16_t)a.y, (bf16_t)a.z, (bf16_t)a.w,
                         (bf16_t)b.x, (bf16_t)b.y, (bf16_t)b.z, (bf16_t)b.w };
            *(bf16x8*)&Wl[wr][wkb + 8 * j] = v;
        }
    }

    f32x4 acc[4][4];
    #pragma unroll
    for (int i = 0; i < 4; ++i)
        #pragma unroll
        for (int j = 0; j < 4; ++j) acc[i][j] = 0.f;

    XT xr[32];
    auto loadX = [&](int t) {
        const XT* xp = Xb + (long)(t * 32) * N_PIX + n0 + tid;
        #pragma unroll
        for (int g = 0; g < 32; ++g) xr[g] = xp[(long)g * N_PIX];
    };

    loadX(0);
    for (int t = 0; t < 6; ++t) {
        // write prefetched regs -> LDS (column tid)
        #pragma unroll
        for (int g = 0; g < 8; ++g) {
            bf16x4 v = { (bf16_t)xr[4 * g + 0], (bf16_t)xr[4 * g + 1],
                         (bf16_t)xr[4 * g + 2], (bf16_t)xr[4 * g + 3] };
            *(bf16x4*)&Xl[tid][g * 4] = v;
        }
        __syncthreads();
        if (t < 5) loadX(t + 1);    // issue next tile's loads under the MFMAs
        bf16x8 af[4], bfr[4];
        #pragma unroll
        for (int mi = 0; mi < 4; ++mi) {
            bf16x4 lo = *(const bf16x4*)&Wl[16 * mi + li][32 * t + 4 * gi];
            bf16x4 hi = *(const bf16x4*)&Wl[16 * mi + li][32 * t + 16 + 4 * gi];
            af[mi] = __builtin_shufflevector(lo, hi, 0, 1, 2, 3, 4, 5, 6, 7);
        }
        #pragma unroll
        for (int ni = 0; ni < 4; ++ni) {
            const int n = 64 * w + 16 * ni + li;
            bf16x4 lo = *(const bf16x4*)&Xl[n][4 * gi];
            bf16x4 hi = *(const bf16x4*)&Xl[n][16 + 4 * gi];
            bfr[ni] = __builtin_shufflevector(lo, hi, 0, 1, 2, 3, 4, 5, 6, 7);
        }
        #pragma unroll
        for (int mi = 0; mi < 4; ++mi)
            #pragma unroll
            for (int ni = 0; ni < 4; ++ni)
                acc[mi][ni] = __builtin_amdgcn_mfma_f32_16x16x32_bf16(
                    af[mi], bfr[ni], acc[mi][ni], 0, 0, 0);
        __syncthreads();
    }
    #pragma unroll
    for (int mi = 0; mi < 4; ++mi)
        #pragma unroll
        for (int ni = 0; ni < 4; ++ni) {
            const int n = n0 + 64 * w + 16 * ni + li;
            #pragma unroll
            for (int r = 0; r < 4; ++r) {
                const int m = m0 + 16 * mi + 4 * gi + r;
                Yb[(long)m * N_PIX + n] = (YT)acc[mi][ni][r];
            }
        }
}

// ---------------- depthwise 3x3, pad 1 — bf16 in/out, 8-wide strips ----------
__global__ __launch_bounds__(256) void dwconv3b(const bf16_t* __restrict__ Yin,
    const float* __restrict__ wdw, bf16_t* __restrict__ Z)
{
    const int ch = blockIdx.x, sb = blockIdx.y;
    const int tid = threadIdx.x;
    const int x0 = (tid & 15) << 3;          // 16 col-groups x 8
    const int y0 = (tid >> 4) << 3;          // 16 row-strips x 8
    const bf16_t* __restrict__ inp = Yin + (long)(sb * C3 + ch) * N_PIX;
    bf16_t* __restrict__ outp = Z + (long)(sb * C3 + ch) * N_PIX;
    const float* wch = wdw + ch * 9;
    const float w00 = wch[0], w01 = wch[1], w02 = wch[2];
    const float w10 = wch[3], w11 = wch[4], w12 = wch[5];
    const float w20 = wch[6], w21 = wch[7], w22 = wch[8];
    const bool hasL = (x0 > 0), hasR = (x0 < 120);
    float A[10], B[10], Cr[10];   // [0]=x0-1, [1..8]=x0..x0+7, [9]=x0+8
    auto loadrow = [&](int yy, float* r) {
        if (yy < 0 || yy > 127) {
            #pragma unroll
            for (int i = 0; i < 10; ++i) r[i] = 0.f;
            return;
        }
        const bf16_t* p = inp + (yy << 7);
        bf16x8 v = *(const bf16x8*)(p + x0);
        #pragma unroll
        for (int j = 0; j < 8; ++j) r[1 + j] = (float)v[j];
        r[0] = hasL ? (float)p[x0 - 1] : 0.f;
        r[9] = hasR ? (float)p[x0 + 8] : 0.f;
    };
    loadrow(y0 - 1, A);
    loadrow(y0,     B);
    #pragma unroll
    for (int r = 0; r < 8; ++r) {
        loadrow(y0 + r + 1, Cr);
        bf16x8 ov;
        #pragma unroll
        for (int i = 0; i < 8; ++i) {
            float s;
            s = fmaf(w00, A[i],  fmaf(w01, A[i + 1],  w02 * A[i + 2]));
            s = fmaf(w10, B[i],  fmaf(w11, B[i + 1],  fmaf(w12, B[i + 2], s)));
            s = fmaf(w20, Cr[i], fmaf(w21, Cr[i + 1], fmaf(w22, Cr[i + 2], s)));
            ov[i] = (bf16_t)s;
        }
        *(bf16x8*)(outp + ((y0 + r) << 7) + x0) = ov;
        #pragma unroll
        for (int i = 0; i < 10; ++i) { A[i] = B[i]; B[i] = Cr[i]; }
    }
}

// ---------------- row inverse L2 norms for q,k (bf16 input) ----------------
__global__ __launch_bounds__(256) void rownorm(const bf16_t* __restrict__ Z,
                                               float* __restrict__ invn)
{
    const int row = blockIdx.x;             // [0, 2*4*384)
    const int s = row / 1536;
    const int b = (row / 384) & 3;
    const int cc = row % 384;
    const bf16_t* p = Z + (long)((s * 4 + b) * C3 + cc) * N_PIX;
    const int tid = threadIdx.x;
    float ss = 0.f;
    for (int i = tid * 8; i < N_PIX; i += 2048) {
        bf16x8 v = *(const bf16x8*)(p + i);
        #pragma unroll
        for (int j = 0; j < 8; ++j) {
            const float f = (float)v[j];
            ss = fmaf(f, f, ss);
        }
    }
    #pragma unroll
    for (int off = 32; off > 0; off >>= 1) ss += __shfl_down(ss, off);
    __shared__ float red[4];
    if ((tid & 63) == 0) red[tid >> 6] = ss;
    __syncthreads();
    if (tid == 0) {
        float t = red[0] + red[1] + red[2] + red[3];
        invn[row] = 1.f / fmaxf(sqrtf(t), 1e-12f);
    }
}

// ---------------- MFMA score partials: all 4 combos share one LDS stage ------
// block = (chunk, b*4+h); wave m = combo (ee, dd, ed, de).
__global__ __launch_bounds__(256) void scores_mfma(const bf16_t* __restrict__ Z,
                                                   float* __restrict__ part)
{
    const int c = blockIdx.x;
    const int bh = blockIdx.y;
    const int b = bh >> 2, h = bh & 3;
    __shared__ __align__(16) bf16_t T[4][48][72];   // qe, qd, ke, kd
    const int tid = threadIdx.x;
    const int m = tid >> 6;
    const int gi = (tid >> 4) & 3, li = tid & 15;
    const int qs = (m == 1 || m == 3) ? 1 : 0;
    const int ks = (m == 1 || m == 2) ? 1 : 0;
    f32x4 acc[3][3];
    #pragma unroll
    for (int i = 0; i < 3; ++i)
        #pragma unroll
        for (int j = 0; j < 3; ++j) acc[i][j] = 0.f;

    const int nbase = c * CHUNK;
    for (int k0 = 0; k0 < CHUNK; k0 += 64) {
        __syncthreads();
        for (int l = tid; l < 1536; l += 256) {
            const int t = l / 384;
            const int rem = l - t * 384;
            const int r = rem >> 3, s = rem & 7;
            const int sidx = (t < 2) ? t : (t - 2);
            const int qk = (t < 2) ? 0 : 1;
            const bf16_t* gp = Z + ((long)((sidx * 4 + b) * C3 + qk * 192 + h * 48 + r)) * N_PIX
                                 + nbase + k0 + s * 8;
            *(bf16x8*)&T[t][r][s * 8] = *(const bf16x8*)gp;
        }
        __syncthreads();
        #pragma unroll
        for (int k2 = 0; k2 < 64; k2 += 32) {
            bf16x8 af[3], bfr[3];
            #pragma unroll
            for (int i = 0; i < 3; ++i) {
                bf16x4 lo = *(const bf16x4*)&T[qs][16 * i + li][k2 + 4 * gi];
                bf16x4 hi = *(const bf16x4*)&T[qs][16 * i + li][k2 + 16 + 4 * gi];
                af[i] = __builtin_shufflevector(lo, hi, 0, 1, 2, 3, 4, 5, 6, 7);
            }
            #pragma unroll
            for (int j = 0; j < 3; ++j) {
                bf16x4 lo = *(const bf16x4*)&T[2 + ks][16 * j + li][k2 + 4 * gi];
                bf16x4 hi = *(const bf16x4*)&T[2 + ks][16 * j + li][k2 + 16 + 4 * gi];
                bfr[j] = __builtin_shufflevector(lo, hi, 0, 1, 2, 3, 4, 5, 6, 7);
            }
            #pragma unroll
            for (int i = 0; i < 3; ++i)
                #pragma unroll
                for (int j = 0; j < 3; ++j)
                    acc[i][j] = __builtin_amdgcn_mfma_f32_16x16x32_bf16(
                        af[i], bfr[j], acc[i][j], 0, 0, 0);
        }
    }
    const long base = ((long)(m * 16 + bh) * NCH + c) * 2304;
    #pragma unroll
    for (int i = 0; i < 3; ++i)
        #pragma unroll
        for (int j = 0; j < 3; ++j) {
            const int e = 16 * j + li;
            #pragma unroll
            for (int r = 0; r < 4; ++r) {
                const int d = 16 * i + 4 * gi + r;
                part[base + d * 48 + e] = acc[i][j][r];
            }
        }
}

// ---------------- reduce partials, scale by norms+temperature, softmax -------
__global__ __launch_bounds__(256) void reduce_softmax(const float* __restrict__ part,
    const float* __restrict__ invn, const float* __restrict__ temp,
    float* __restrict__ attn)
{
    const int mbh = blockIdx.x;                 // 64
    const int m = mbh >> 4, b = (mbh >> 2) & 3, h = mbh & 3;
    const int qs = (m == 1 || m == 3) ? 1 : 0;
    const int ks = (m == 1 || m == 2) ? 1 : 0;
    __shared__ float sm[48][48];
    const int tid = threadIdx.x;
    const long pbase = (long)mbh * NCH * 2304;
    const float T = temp[h];
    for (int idx = tid; idx < 2304; idx += 256) {
        float v = 0.f;
        #pragma unroll 8
        for (int c = 0; c < NCH; ++c) v += part[pbase + c * 2304 + idx];
        const int d = idx / 48, e = idx % 48;
        const float iq = invn[(qs * 4 + b) * 384 + h * 48 + d];
        const float ik = invn[(ks * 4 + b) * 384 + 192 + h * 48 + e];
        sm[d][e] = v * iq * ik * T;
    }
    __syncthreads();
    if (tid < 48) {
        float mx = -1e30f;
        #pragma unroll
        for (int e = 0; e < 48; ++e) mx = fmaxf(mx, sm[tid][e]);
        float sum = 0.f;
        #pragma unroll
        for (int e = 0; e < 48; ++e) {
            const float v = __expf(sm[tid][e] - mx);
            sm[tid][e] = v;
            sum += v;
        }
        const float inv = 1.f / sum;
        const long abase = (long)mbh * 2304 + (long)tid * 48;
        #pragma unroll
        for (int e = 0; e < 48; ++e) attn[abase + e] = sm[tid][e] * inv;
    }
}

// ---------------- fold attn into projection: M[m][b][o][h*48+e] --------------
// m==3 (inter_de): einsum '...de,bhen->bhdn' SUMS the ellipsis dims.
__global__ __launch_bounds__(256) void make_M(const float* __restrict__ attn,
                                              WPtrs wp, float* __restrict__ M)
{
    const int h = blockIdx.x & 3;
    const int b = (blockIdx.x >> 2) & 3;
    const int m = blockIdx.x >> 4;              // grid 64
    __shared__ float A[48][48];
    const int tid = threadIdx.x;
    if (m == 3) {
        for (int l = tid; l < 2304; l += 256) {
            float s = 0.f;
            #pragma unroll
            for (int bb = 0; bb < 16; ++bb)
                s += attn[(long)(48 + bb) * 2304 + l];
            A[l / 48][l % 48] = s;
        }
    } else {
        const long ab = (long)(m * 16 + b * 4 + h) * 2304;
        for (int l = tid; l < 2304; l += 256)
            A[l / 48][l % 48] = attn[ab + l];
    }
    __syncthreads();
    const float* W = wp.p[m];
    float* Mo = M + (long)(m * 4 + b) * 192 * 192;
    for (int o = tid >> 4; o < 192; o += 16) {
        const float* wrow = W + (long)o * 192 + h * 48;
        for (int e2 = tid & 15; e2 < 48; e2 += 16) {
            float s = 0.f;
            #pragma unroll
            for (int d = 0; d < 48; ++d) s = fmaf(wrow[d], A[d][e2], s);
            Mo[(long)o * 192 + h * 48 + e2] = s;
        }
    }
}

extern "C" void kernel_launch(void* const* d_in, const int* in_sizes, int n_in,
                              void* d_out, int out_size, void* d_ws, size_t ws_size,
                              hipStream_t stream)
{
    const float* e     = (const float*)d_in[0];
    const float* d     = (const float*)d_in[1];
    const float* temp  = (const float*)d_in[2];
    const float* w_qkv = (const float*)d_in[3];
    const float* w_dw  = (const float*)d_in[4];
    const float* w_p1  = (const float*)d_in[5];
    const float* w_p2  = (const float*)d_in[6];
    const float* w_p3  = (const float*)d_in[7];
    const float* w_p4  = (const float*)d_in[8];
    float* out = (float*)d_out;
    float* ws  = (float*)d_ws;

    // workspace layout (float units)
    bf16_t* zraw = (bf16_t*)ws;             // 75,497,472 bf16 (qkv raw) = 37,748,736 f32
    bf16_t* zb   = (bf16_t*)(ws + 37748736L);  // 75,497,472 bf16
    float* attn  = ws + 75497472L;          // 147,456
    float* invn  = ws + 75644928L;          // 3,072
    // part & M reuse the zraw region once it's dead (after dwconv3b)
    float* part  = ws;                      // 4,718,592 f32
    float* Mmat  = ws + 8388608L;           // 589,824 f32

    const long sXin = (long)CC * N_PIX;
    const long sQKV = (long)C3 * N_PIX;

    // 1) pointwise qkv GEMM, bf16 output
    GArgs gq{};
    for (int bt = 0; bt < 16; ++bt) { gq.W[bt] = w_qkv; gq.xoff[bt] = (long)(bt & 3) * sXin; }
    gemm_k192<float, bf16_t><<<dim3(64, 9, 4), 256, 0, stream>>>(gq, e, zraw, sQKV);
    gemm_k192<float, bf16_t><<<dim3(64, 9, 4), 256, 0, stream>>>(gq, d, zraw + 4L * sQKV, sQKV);
    // 2) depthwise 3x3 (bf16 -> bf16)
    dwconv3b<<<dim3(C3, 8), 256, 0, stream>>>(zraw, w_dw, zb);
    // 3) inverse L2 norms for q,k rows
    rownorm<<<dim3(3072), 256, 0, stream>>>(zb, invn);
    // 4) MFMA score partials, 4 combos fused (part reuses dead zraw region)
    scores_mfma<<<dim3(NCH, 16), 256, 0, stream>>>(zb, part);
    // 5) reduce + scale + softmax
    reduce_softmax<<<dim3(64), 256, 0, stream>>>(part, invn, temp, attn);
    // 6) fold attn into projection matrices
    WPtrs wpj; wpj.p[0] = w_p1; wpj.p[1] = w_p2; wpj.p[2] = w_p3; wpj.p[3] = w_p4;
    make_M<<<dim3(64), 256, 0, stream>>>(attn, wpj, Mmat);
    // 7) fused (proj ∘ attn) @ V directly into d_out (V is bf16)
    GArgs gm{};
    for (int bt = 0; bt < 16; ++bt) {
        const int m = bt >> 2, b = bt & 3;
        const int ks = (m == 1 || m == 2) ? 1 : 0;
        gm.W[bt] = Mmat + (long)bt * 192 * 192;
        gm.xoff[bt] = ((long)((ks * 4 + b) * C3 + 384)) * N_PIX;
    }
    gemm_k192<bf16_t, float><<<dim3(64, 3, 16), 256, 0, stream>>>(gm, zb, out, sXin);
}